// Round 6
// baseline (5690.887 us; speedup 1.0000x reference)
//
#include <hip/hip_runtime.h>
#include <math.h>

#define T_SEQ 120
#define BATCH 256
#define HID   512
#define G3    1536            // 3*HID
#define MROWS (BATCH*T_SEQ)   // 30720
#define TS    (T_SEQ*HID)     // 61440, row stride per batch in out buffers
#define KGATE 122880          // T_SEQ*2*HID
#define HDEPTH 4              // h0 ring depth
#define FSTRIDE 16            // flag stride (ints) -> one flag per 64B line

typedef __attribute__((ext_vector_type(8))) short bf16x8;
typedef __attribute__((ext_vector_type(4))) float f32x4;

__device__ __forceinline__ unsigned short f2bf(float f) {
    union { float f; unsigned u; } x; x.f = f;
    unsigned r = x.u + 0x7fffu + ((x.u >> 16) & 1u);   // RNE
    return (unsigned short)(r >> 16);
}
__device__ __forceinline__ float bf2f(unsigned short u) {
    union { unsigned u; float f; } x; x.u = ((unsigned)u) << 16; return x.f;
}
__device__ __forceinline__ float sigm_fast(float x) {
    return 1.f / (1.f + __expf(-x));
}
__device__ __forceinline__ float tanh_fast(float x) {
    float e = __expf(2.f * x);
    return 1.f - 2.f / (e + 1.f);
}

// ---------------------------------------------------------------------------
// build x_in[m=b*120+t][d] = concat(X_lag, X_cov)[t,b,d]
// ---------------------------------------------------------------------------
__global__ void build_x(const float* __restrict__ X_lag,
                        const float* __restrict__ X_cov,
                        float* __restrict__ x_in)
{
    int idx = blockIdx.x * 256 + threadIdx.x;      // < 30720*64
    int d = idx & 63;
    int m = idx >> 6;                               // b*120 + t
    int b = m / 120, t = m - b * 120;
    float v;
    if (d < 32) v = X_lag[((size_t)t * BATCH + b) * 32 + d];
    else        v = X_cov[((size_t)t * BATCH + b) * 32 + (d - 32)];
    x_in[idx] = v;
}

__global__ void cast_whh0(const float* __restrict__ W, unsigned short* __restrict__ o)
{
    int i = blockIdx.x * 256 + threadIdx.x;        // < 786432
    o[i] = f2bf(W[i]);
}

// Wcat1 [1536][1024]: cols 0..511 = W_hh1, cols 512..1023 = W_ih1
__global__ void cast_wcat1(const float* __restrict__ Whh, const float* __restrict__ Wih,
                           unsigned short* __restrict__ o)
{
    int i = blockIdx.x * 256 + threadIdx.x;        // < 1572864
    int row = i >> 10, c = i & 1023;
    float v = (c < 512) ? Whh[row * 512 + c] : Wih[row * 512 + (c - 512)];
    o[i] = f2bf(v);
}

__global__ void mkbias(const float* __restrict__ bih0, const float* __restrict__ bhh0,
                       const float* __restrict__ bih1, const float* __restrict__ bhh1,
                       float* __restrict__ bcomb0, float* __restrict__ bc1)
{
    int n = blockIdx.x * 256 + threadIdx.x;        // < 1536
    bcomb0[n] = bih0[n] + (n < 1024 ? bhh0[n] : 0.f);
    bc1[n]    = bih1[n] + (n < 1024 ? bhh1[n] : 0.f);
}

// ---------------------------------------------------------------------------
// Tiled f32 GEMM, bf16 TRANSPOSED write for gx0:
// C[(t*256+b)*1536 + n] = bf16(bias[n] + sum_k A[m=b*120+t][k]*B[n][k])
// ---------------------------------------------------------------------------
__global__ __launch_bounds__(256) void gemm_abt_t(
    const float* __restrict__ A, const float* __restrict__ B,
    const float* __restrict__ bias, unsigned short* __restrict__ C,
    int M, int N, int K)
{
    __shared__ float As[32][129];
    __shared__ float Bs[32][129];
    int m0 = blockIdx.x * 128;
    int n0 = blockIdx.y * 128;
    int tid = threadIdx.x;
    int tx = tid & 15, ty = tid >> 4;
    float acc[8][8] = {};
    for (int k0 = 0; k0 < K; k0 += 32) {
        #pragma unroll
        for (int i = 0; i < 16; i++) {
            int e = tid + i * 256;
            int row = e >> 5, col = e & 31;
            As[col][row] = A[(size_t)(m0 + row) * K + k0 + col];
            Bs[col][row] = B[(size_t)(n0 + row) * K + k0 + col];
        }
        __syncthreads();
        #pragma unroll
        for (int kk = 0; kk < 32; kk++) {
            float a[8], b[8];
            #pragma unroll
            for (int i = 0; i < 8; i++) a[i] = As[kk][ty + i * 16];
            #pragma unroll
            for (int j = 0; j < 8; j++) b[j] = Bs[kk][tx + j * 16];
            #pragma unroll
            for (int i = 0; i < 8; i++)
                #pragma unroll
                for (int j = 0; j < 8; j++) acc[i][j] += a[i] * b[j];
        }
        __syncthreads();
    }
    #pragma unroll
    for (int i = 0; i < 8; i++) {
        int m = m0 + ty + i * 16;
        int b = m / 120, t = m - b * 120;
        #pragma unroll
        for (int j = 0; j < 8; j++) {
            int n = n0 + tx + j * 16;
            C[((size_t)t * 256 + b) * G3 + n] = f2bf(acc[i][j] + bias[n]);
        }
    }
}

// ---------------------------------------------------------------------------
// Persistent recurrence: 64 blocks x 512 threads (8 waves), 1 block/CU.
// blocks [0,32): layer0, j-tile jb (16 cols), all 256 batches.
// blocks [32,64): layer1, same j split; K-concat [h1|h0] fuses Wih1 GEMM.
// Weights for the block's 48 rows live in LDS (XOR-swizzled) for all steps.
// Wave wv owns batches [wv*32, wv*32+32); f32 carry in registers.
// Sync: per-block flags (release/acquire + __threadfence), layer1 self-paces;
// h0 ring depth 4 lets layer0 run ahead; bounded spin prevents hangs.
// ---------------------------------------------------------------------------
__device__ __forceinline__ bool wait_flags(const int* __restrict__ f0,
                                           const int* __restrict__ f1,
                                           int thr0, int thr1, int lane)
{
    const int* ap = (lane < 32) ? (f0 + lane * FSTRIDE)
                                : (f1 + (lane - 32) * FSTRIDE);
    int thr = (lane < 32) ? thr0 : thr1;
    for (int it = 0; it < 400000; ++it) {
        int v = __hip_atomic_load(ap, __ATOMIC_RELAXED, __HIP_MEMORY_SCOPE_AGENT);
        if (__all(v >= thr)) return true;
        __builtin_amdgcn_s_sleep(8);
    }
    return false;   // hang-guard: proceed (results wrong, but terminates)
}

__global__ __launch_bounds__(512) void gru_persist2(
    const unsigned short* __restrict__ gx0,          // [120][256][1536] bf16
    const unsigned short* __restrict__ Whh0,         // [1536][512] bf16
    const unsigned short* __restrict__ Wcat1,        // [1536][1024] bf16
    const float* __restrict__ bhh0,
    const float* __restrict__ bhh1,
    const float* __restrict__ bc1,
    unsigned short* __restrict__ h0r,                // [HDEPTH][256][512]
    unsigned short* __restrict__ h1r,                // [2][256][512]
    float* __restrict__ out0, float* __restrict__ out1,
    int* __restrict__ flag0, int* __restrict__ flag1)
{
    __shared__ unsigned short wlds[48 * 1024];       // 96 KiB (layer0 uses half)
    const int tid  = threadIdx.x;
    const int wv   = tid >> 6, lane = tid & 63;
    const int l15  = lane & 15, l4 = lane >> 4;
    const int layer = blockIdx.x >> 5;
    const int jb   = blockIdx.x & 31;
    const int j    = jb * 16 + l15;
    const int b0   = wv * 32;
    const int sw   = (l15 & 7) << 3;                 // XOR swizzle (elements)

    if (!layer) {
        // ---- stage weights: 48 rows x 512, swizzled ----
        for (int c = tid; c < 48 * 64; c += 512) {   // 16B chunks
            int lr = c >> 6, ck = c & 63;
            int eoff = ck * 8;
            int grow = ((lr >> 4) * 512) + jb * 16 + (lr & 15);
            bf16x8 v = *(const bf16x8*)(Whh0 + (size_t)grow * 512 + eoff);
            int loff = (lr * 512 + eoff) ^ ((lr & 7) << 3);
            *(bf16x8*)&wlds[loff] = v;
        }
        const float bn0 = bhh0[1024 + j];
        float carry[2][4] = {};
        __syncthreads();

        for (int t = 0; t < T_SEQ; t++) {
            // need all h0(t-1) ready; ring slot t&3 free once layer1 >= t-HDEPTH
            wait_flags(flag0, flag1, t - 1, t - HDEPTH, lane);
            __threadfence();

            f32x4 a0[2], a1[2], a2[2];
            #pragma unroll
            for (int u = 0; u < 2; u++) {
                a0[u] = (f32x4){0.f,0.f,0.f,0.f};
                a1[u] = (f32x4){0.f,0.f,0.f,0.f};
                a2[u] = (f32x4){0.f,0.f,0.f,0.f};
            }
            if (t > 0) {
                const unsigned short* hp = h0r + (size_t)((t - 1) & 3) * (256 * 512);
                #pragma unroll
                for (int ks = 0; ks < 16; ks++) {
                    const int ko = ks * 32 + 8 * l4;
                    bf16x8 B0 = *(const bf16x8*)&wlds[((l15)      * 512 + ko) ^ sw];
                    bf16x8 B1 = *(const bf16x8*)&wlds[((16 + l15) * 512 + ko) ^ sw];
                    bf16x8 B2 = *(const bf16x8*)&wlds[((32 + l15) * 512 + ko) ^ sw];
                    #pragma unroll
                    for (int u = 0; u < 2; u++) {
                        bf16x8 A = *(const bf16x8*)(hp + (size_t)(b0 + u * 16 + l15) * 512 + ko);
                        a0[u] = __builtin_amdgcn_mfma_f32_16x16x32_bf16(A, B0, a0[u], 0, 0, 0);
                        a1[u] = __builtin_amdgcn_mfma_f32_16x16x32_bf16(A, B1, a1[u], 0, 0, 0);
                        a2[u] = __builtin_amdgcn_mfma_f32_16x16x32_bf16(A, B2, a2[u], 0, 0, 0);
                    }
                }
            }
            unsigned short* hw = h0r + (size_t)(t & 3) * (256 * 512);
            #pragma unroll
            for (int u = 0; u < 2; u++) {
                #pragma unroll
                for (int rr = 0; rr < 4; rr++) {
                    int b = b0 + u * 16 + 4 * l4 + rr;
                    const unsigned short* gp = gx0 + ((size_t)t * 256 + b) * G3 + j;
                    float r = sigm_fast(bf2f(gp[0])   + a0[u][rr]);
                    float z = sigm_fast(bf2f(gp[512]) + a1[u][rr]);
                    float n = tanh_fast(bf2f(gp[1024]) + r * (a2[u][rr] + bn0));
                    float h = (1.f - z) * n + z * carry[u][rr];
                    carry[u][rr] = h;
                    out0[(size_t)b * TS + (size_t)t * 512 + j] = h;
                    hw[(size_t)b * 512 + j] = f2bf(h);
                }
            }
            __threadfence();
            __syncthreads();
            if (tid == 0)
                __hip_atomic_store(flag0 + jb * FSTRIDE, t, __ATOMIC_RELEASE,
                                   __HIP_MEMORY_SCOPE_AGENT);
        }
    } else {
        // ---- stage weights: 48 rows x 1024, swizzled ----
        for (int c = tid; c < 48 * 128; c += 512) {  // 16B chunks
            int lr = c >> 7, ck = c & 127;
            int eoff = ck * 8;
            int grow = ((lr >> 4) * 512) + jb * 16 + (lr & 15);
            bf16x8 v = *(const bf16x8*)(Wcat1 + (size_t)grow * 1024 + eoff);
            int loff = (lr * 1024 + eoff) ^ ((lr & 7) << 3);
            *(bf16x8*)&wlds[loff] = v;
        }
        const float br = bc1[j], bz = bc1[512 + j];
        const float bnx = bc1[1024 + j], bn = bhh1[1024 + j];
        float carry[2][4] = {};
        __syncthreads();

        for (int tau = 0; tau < T_SEQ; tau++) {
            wait_flags(flag0, flag1, tau, tau - 1, lane);
            __threadfence();

            f32x4 a0[2], a1[2], a2[2], a3[2];
            #pragma unroll
            for (int u = 0; u < 2; u++) {
                a0[u] = (f32x4){0.f,0.f,0.f,0.f};
                a1[u] = (f32x4){0.f,0.f,0.f,0.f};
                a2[u] = (f32x4){0.f,0.f,0.f,0.f};
                a3[u] = (f32x4){0.f,0.f,0.f,0.f};
            }
            if (tau > 0) {                           // h-part: h1(tau-1), cols [0,512)
                const unsigned short* hp = h1r + (size_t)((tau - 1) & 1) * (256 * 512);
                #pragma unroll
                for (int ks = 0; ks < 16; ks++) {
                    const int ko = ks * 32 + 8 * l4;
                    bf16x8 B0 = *(const bf16x8*)&wlds[((l15)      * 1024 + ko) ^ sw];
                    bf16x8 B1 = *(const bf16x8*)&wlds[((16 + l15) * 1024 + ko) ^ sw];
                    bf16x8 B2 = *(const bf16x8*)&wlds[((32 + l15) * 1024 + ko) ^ sw];
                    #pragma unroll
                    for (int u = 0; u < 2; u++) {
                        bf16x8 A = *(const bf16x8*)(hp + (size_t)(b0 + u * 16 + l15) * 512 + ko);
                        a0[u] = __builtin_amdgcn_mfma_f32_16x16x32_bf16(A, B0, a0[u], 0, 0, 0);
                        a1[u] = __builtin_amdgcn_mfma_f32_16x16x32_bf16(A, B1, a1[u], 0, 0, 0);
                        a2[u] = __builtin_amdgcn_mfma_f32_16x16x32_bf16(A, B2, a2[u], 0, 0, 0);
                    }
                }
            }
            {                                        // x-part: h0(tau), cols [512,1024)
                const unsigned short* hx = h0r + (size_t)(tau & 3) * (256 * 512);
                #pragma unroll
                for (int ks = 0; ks < 16; ks++) {
                    const int ko = ks * 32 + 8 * l4;
                    bf16x8 B0 = *(const bf16x8*)&wlds[((l15)      * 1024 + 512 + ko) ^ sw];
                    bf16x8 B1 = *(const bf16x8*)&wlds[((16 + l15) * 1024 + 512 + ko) ^ sw];
                    bf16x8 B2 = *(const bf16x8*)&wlds[((32 + l15) * 1024 + 512 + ko) ^ sw];
                    #pragma unroll
                    for (int u = 0; u < 2; u++) {
                        bf16x8 A = *(const bf16x8*)(hx + (size_t)(b0 + u * 16 + l15) * 512 + ko);
                        a0[u] = __builtin_amdgcn_mfma_f32_16x16x32_bf16(A, B0, a0[u], 0, 0, 0);
                        a1[u] = __builtin_amdgcn_mfma_f32_16x16x32_bf16(A, B1, a1[u], 0, 0, 0);
                        a3[u] = __builtin_amdgcn_mfma_f32_16x16x32_bf16(A, B2, a3[u], 0, 0, 0);
                    }
                }
            }
            unsigned short* hw = h1r + (size_t)(tau & 1) * (256 * 512);
            #pragma unroll
            for (int u = 0; u < 2; u++) {
                #pragma unroll
                for (int rr = 0; rr < 4; rr++) {
                    int b = b0 + u * 16 + 4 * l4 + rr;
                    float r = sigm_fast(a0[u][rr] + br);
                    float z = sigm_fast(a1[u][rr] + bz);
                    float n = tanh_fast(a3[u][rr] + bnx + r * (a2[u][rr] + bn));
                    float h = (1.f - z) * n + z * carry[u][rr];
                    carry[u][rr] = h;
                    out1[(size_t)b * TS + (size_t)tau * 512 + j] = h;
                    hw[(size_t)b * 512 + j] = f2bf(h);
                }
            }
            __threadfence();
            __syncthreads();
            if (tid == 0)
                __hip_atomic_store(flag1 + jb * FSTRIDE, tau, __ATOMIC_RELEASE,
                                   __HIP_MEMORY_SCOPE_AGENT);
        }
    }
}

// ---------------------------------------------------------------------------
// z partials: 960 blocks = (t, half, c-quarter of 128).   [verified round 4/5]
// ---------------------------------------------------------------------------
__global__ __launch_bounds__(256) void zpart_kernel(
    const float* __restrict__ out, const float* __restrict__ Gw,
    float* __restrict__ zp)
{
    __shared__ float Os[128][33];
    __shared__ float Gs[128][33];
    int bk = blockIdx.x;
    int t = bk >> 3, half = (bk >> 2) & 1, cq = bk & 3;
    int tid = threadIdx.x;
    int tx = tid & 15, ty = tid >> 4;
    float acc[8][8] = {};
    int cbase = cq * 128;
    for (int c0 = cbase; c0 < cbase + 128; c0 += 32) {
        #pragma unroll
        for (int i = 0; i < 16; i++) {
            int e = tid + i * 256;
            int row = e >> 5, col = e & 31;
            Os[row][col] = out[(size_t)(row + half * 128) * TS + (size_t)t * 512 + c0 + col];
            float v = 0.f;
            if (row < 120)
                v = Gw[(size_t)row * KGATE + (size_t)t * 1024 + half * 512 + c0 + col];
            Gs[row][col] = v;
        }
        __syncthreads();
        #pragma unroll
        for (int kk = 0; kk < 32; kk++) {
            float a[8], g[8];
            #pragma unroll
            for (int i = 0; i < 8; i++) a[i] = Os[ty + i * 16][kk];
            #pragma unroll
            for (int j = 0; j < 8; j++) g[j] = Gs[tx + j * 16][kk];
            #pragma unroll
            for (int i = 0; i < 8; i++)
                #pragma unroll
                for (int j = 0; j < 8; j++) acc[i][j] += a[i] * g[j];
        }
        __syncthreads();
    }
    float* zb = zp + (size_t)bk * (128 * 120);
    #pragma unroll
    for (int i = 0; i < 8; i++) {
        int ii = ty + i * 16;
        #pragma unroll
        for (int j = 0; j < 8; j++) {
            int r = tx + j * 16;
            if (r < 120) zb[ii * 120 + r] = acc[i][j];
        }
    }
}

__global__ void zreduce(const float* __restrict__ zp,
                        const float* __restrict__ gate_b_l,
                        float* __restrict__ z)
{
    int idx = blockIdx.x * 256 + threadIdx.x;
    if (idx >= 128 * 120) return;
    float s = 0.f;
    for (int c = 0; c < 960; c++) s += zp[(size_t)c * (128 * 120) + idx];
    z[idx] = s + gate_b_l[idx % 120];
}

__global__ __launch_bounds__(128) void bn_col(
    const float* __restrict__ z, const float* __restrict__ gamma,
    const float* __restrict__ beta, float* __restrict__ wm)
{
    int r = blockIdx.x, i = threadIdx.x;
    __shared__ float sh[2];
    float v = z[i * 120 + r];
    float s = v;
    for (int o = 32; o > 0; o >>= 1) s += __shfl_down(s, o);
    if ((i & 63) == 0) sh[i >> 6] = s;
    __syncthreads();
    float m = (sh[0] + sh[1]) * (1.f / 128.f);
    __syncthreads();
    float d = (v - m) * (v - m);
    for (int o = 32; o > 0; o >>= 1) d += __shfl_down(d, o);
    if ((i & 63) == 0) sh[i >> 6] = d;
    __syncthreads();
    float var = (sh[0] + sh[1]) * (1.f / 128.f);
    float w = 1.f / (1.f + expf(-(gamma[r] * (v - m) / sqrtf(var + 1e-5f) + beta[r])));
    __syncthreads();
    float ws_ = w;
    for (int o = 32; o > 0; o >>= 1) ws_ += __shfl_down(ws_, o);
    if ((i & 63) == 0) sh[i >> 6] = ws_;
    __syncthreads();
    if (i == 0) wm[r] = (sh[0] + sh[1]) * (1.f / 128.f);
}

__global__ __launch_bounds__(128) void softmax120(
    const float* __restrict__ wm, float* __restrict__ g_out,
    float* __restrict__ g_ws)
{
    int i = threadIdx.x;
    __shared__ float sh[2];
    float v = (i < 120) ? wm[i] : -1e30f;
    float m = v;
    for (int o = 32; o > 0; o >>= 1) m = fmaxf(m, __shfl_down(m, o));
    if ((i & 63) == 0) sh[i >> 6] = m;
    __syncthreads();
    float mx = fmaxf(sh[0], sh[1]);
    float e = (i < 120) ? expf(v - mx) : 0.f;
    __syncthreads();
    float se = e;
    for (int o = 32; o > 0; o >>= 1) se += __shfl_down(se, o);
    if ((i & 63) == 0) sh[i >> 6] = se;
    __syncthreads();
    float sum = sh[0] + sh[1];
    if (i < 120) { float g = e / sum; g_out[i] = g; g_ws[i] = g; }
}

__global__ void halfmeans(const float* __restrict__ out,
                          float* __restrict__ ms, float* __restrict__ mt)
{
    int idx = blockIdx.x * 256 + threadIdx.x;
    int half = idx >= TS;
    int tc = idx - half * TS;
    const float* base = out + (size_t)(half * 128) * TS + tc;
    float s = 0.f;
    for (int i = 0; i < 128; i++) s += base[(size_t)i * TS];
    s *= (1.f / 128.f);
    if (half) mt[tc] = s; else ms[tc] = s;
}

// coalesced: thread c accumulates over windowed j, block-reduce 512 lanes
__global__ __launch_bounds__(512) void transfer_part(
    const float* __restrict__ ms, const float* __restrict__ mt,
    const float* __restrict__ gw, const int* __restrict__ lenw,
    float* __restrict__ part)
{
    int t = blockIdx.x, c = threadIdx.x;
    int lw = lenw[0];
    int j0 = t - lw; if (j0 < 0) j0 = 0;
    int j1 = t + lw; if (j1 > 119) j1 = 119;
    float m_c = ms[(size_t)t * 512 + c];
    float acc = 0.f;
    for (int j = j0; j <= j1; j++) {
        float d = m_c - mt[(size_t)j * 512 + c];
        acc += d * d;
    }
    for (int o = 32; o > 0; o >>= 1) acc += __shfl_down(acc, o);
    __shared__ float sh[8];
    if ((c & 63) == 0) sh[c >> 6] = acc;
    __syncthreads();
    if (c == 0) {
        float s = 0.f;
        #pragma unroll
        for (int k = 0; k < 8; k++) s += sh[k];
        part[t] = gw[t] * s;
    }
}

// wave-per-row prediction head: grid = dsl*64 blocks, 4 waves each
__global__ __launch_bounds__(256) void yhat_kernel(
    const float* __restrict__ out1, const float* __restrict__ y,
    const float* __restrict__ fcW, const float* __restrict__ fcb,
    int dsl, float* __restrict__ dout, float* __restrict__ lp_rows)
{
    int wid = blockIdx.x * 4 + (threadIdx.x >> 6);   // 0..dsl*256-1
    int lane = threadIdx.x & 63;
    int tt = wid >> 8, b = wid & 255;
    int t = T_SEQ - dsl + tt;
    const float* row = out1 + (size_t)b * TS + (size_t)t * 512;
    float s = 0.f;
    #pragma unroll
    for (int k = 0; k < 8; k++) s += row[lane + 64 * k] * fcW[lane + 64 * k];
    for (int o = 32; o > 0; o >>= 1) s += __shfl_down(s, o);
    if (lane == 0) {
        float loc = s + fcb[0];
        float sp = fmaxf(loc, 0.f) + log1pf(expf(-fabsf(loc)));
        float scale = sp + 1e-6f;
        dout[2 + tt * 256 + b] = loc;
        dout[2 + dsl * 256 + tt * 256 + b] = scale;
        float yt = y[(size_t)t * 256 + b];
        float u = (yt - loc) / scale;
        lp_rows[wid] = -0.5f * u * u - logf(scale) - 0.91893853320467274f;
    }
}

__global__ __launch_bounds__(64) void finalize(
    const float* __restrict__ lp_rows, const float* __restrict__ part0,
    const float* __restrict__ part1, float* __restrict__ dout, int n_lp)
{
    int i = threadIdx.x;
    float s = 0.f;
    for (int k = i; k < n_lp; k += 64) s += lp_rows[k];
    for (int o = 32; o > 0; o >>= 1) s += __shfl_down(s, o);
    float tr = 0.f;
    for (int k = i; k < 120; k += 64) tr += part0[k] + part1[k];
    for (int o = 32; o > 0; o >>= 1) tr += __shfl_down(tr, o);
    if (i == 0) {
        float ly = -s / (float)n_lp;
        dout[1] = ly;
        dout[0] = ly + tr;
    }
}

// ---------------------------------------------------------------------------
extern "C" void kernel_launch(void* const* d_in, const int* in_sizes, int n_in,
                              void* d_out, int out_size, void* d_ws, size_t ws_size,
                              hipStream_t stream)
{
    const float* X_cov  = (const float*)d_in[1];
    const float* X_lag  = (const float*)d_in[2];
    const float* y      = (const float*)d_in[3];
    const int*   lenw   = (const int*)d_in[5];
    const float* W_ih0  = (const float*)d_in[6];
    const float* W_hh0  = (const float*)d_in[7];
    const float* b_ih0  = (const float*)d_in[8];
    const float* b_hh0  = (const float*)d_in[9];
    const float* W_ih1  = (const float*)d_in[10];
    const float* W_hh1  = (const float*)d_in[11];
    const float* b_ih1  = (const float*)d_in[12];
    const float* b_hh1  = (const float*)d_in[13];
    const float* gate_W = (const float*)d_in[14];
    const float* gate_b = (const float*)d_in[15];
    const float* bn_g   = (const float*)d_in[16];
    const float* bn_b   = (const float*)d_in[17];
    const float* fc_W   = (const float*)d_in[18];
    const float* fc_b   = (const float*)d_in[19];
    float* dout = (float*)d_out;
    float* ws   = (float*)d_ws;

    // workspace layout (float offsets). Aliases are time-disjoint:
    //  - zp aliases gx0 (gx0 dead after gru_persist2)
    //  - lp_rows aliases x_in (dead after gemm_abt_t)
    float* x_in    = ws;                          // 1,966,080
    unsigned short* gx0bf = (unsigned short*)(ws + 1966080);      // 47,185,920 ush
    float* out0    = ws + 25559040;               // 15,728,640
    float* out1    = ws + 41287680;               // 15,728,640
    unsigned short* Whh0bf  = (unsigned short*)(ws + 57016320);   // 786,432 ush
    unsigned short* Wcat1bf = (unsigned short*)(ws + 57409536);   // 1,572,864 ush
    unsigned short* h0r     = (unsigned short*)(ws + 58195968);   // 4*131072 ush
    unsigned short* h1r     = (unsigned short*)(ws + 58458112);   // 2*131072 ush
    float* zmat    = ws + 58589184;               // 15,360
    float* wm      = ws + 58604544;               // 120
    float* gw_ws   = ws + 58604664;               // 240
    float* msb     = ws + 58604904;               // 61,440
    float* mtb     = ws + 58666344;               // 61,440
    float* part    = ws + 58727784;               // 240
    float* bcomb0  = ws + 58728024;               // 1536
    float* bc1     = ws + 58729560;               // 1536
    int*   flags   = (int*)(ws + 58731096);       // 1024 ints (2x32 strided)
    float* zp      = ws + 1966080;                // 14,745,600 (alias of gx0)
    float* lp_rows = x_in;                        // dsl*256 (alias)
    int* flag0 = flags;
    int* flag1 = flags + 32 * FSTRIDE;

    int dsl = (out_size - 2 - 2 * T_SEQ) / (2 * BATCH);   // = 24

    build_x<<<dim3(7680), 256, 0, stream>>>(X_lag, X_cov, x_in);
    cast_whh0<<<dim3(3072), 256, 0, stream>>>(W_hh0, Whh0bf);
    cast_wcat1<<<dim3(6144), 256, 0, stream>>>(W_hh1, W_ih1, Wcat1bf);
    mkbias<<<dim3(6), 256, 0, stream>>>(b_ih0, b_hh0, b_ih1, b_hh1, bcomb0, bc1);
    hipMemsetAsync(flags, 0xFF, 1024 * sizeof(int), stream);   // flags = -1

    gemm_abt_t<<<dim3(240, 12), 256, 0, stream>>>(x_in, W_ih0, bcomb0, gx0bf,
                                                  MROWS, G3, 64);

    gru_persist2<<<dim3(64), 512, 0, stream>>>(gx0bf, Whh0bf, Wcat1bf,
                                               b_hh0, b_hh1, bc1,
                                               h0r, h1r, out0, out1,
                                               flag0, flag1);

    for (int l = 0; l < 2; l++) {
        const float* o = l ? out1 : out0;
        zpart_kernel<<<960, 256, 0, stream>>>(o, gate_W + (size_t)l * 120 * KGATE, zp);
        zreduce<<<60, 256, 0, stream>>>(zp, gate_b + l * 120, zmat);
        bn_col<<<120, 128, 0, stream>>>(zmat, bn_g + l * 120, bn_b + l * 120, wm);
        softmax120<<<1, 128, 0, stream>>>(wm, dout + 2 + 2 * dsl * 256 + l * 120,
                                          gw_ws + l * 120);
        halfmeans<<<480, 256, 0, stream>>>(o, msb, mtb);
        transfer_part<<<120, 512, 0, stream>>>(msb, mtb, gw_ws + l * 120, lenw,
                                               part + l * 120);
    }

    yhat_kernel<<<dsl * 64, 256, 0, stream>>>(out1, y, fc_W, fc_b, dsl, dout, lp_rows);
    finalize<<<1, 64, 0, stream>>>(lp_rows, part, part + 120, dout, dsl * 256);
}

// Round 7
// 4171.101 us; speedup vs baseline: 1.3644x; 1.3644x over previous
//
#include <hip/hip_runtime.h>
#include <math.h>

#define T_SEQ 120
#define BATCH 256
#define HID   512
#define G3    1536            // 3*HID
#define MROWS (BATCH*T_SEQ)   // 30720
#define TS    (T_SEQ*HID)     // 61440, row stride per batch in out buffers
#define KGATE 122880          // T_SEQ*2*HID
#define HDEPTH 4              // h0 ring depth
#define FSTRIDE 16            // flag stride (ints) -> one flag per 64B line

typedef __attribute__((ext_vector_type(8))) short bf16x8;
typedef __attribute__((ext_vector_type(4))) float f32x4;
typedef unsigned long long u64;

__device__ __forceinline__ unsigned short f2bf(float f) {
    union { float f; unsigned u; } x; x.f = f;
    unsigned r = x.u + 0x7fffu + ((x.u >> 16) & 1u);   // RNE
    return (unsigned short)(r >> 16);
}
__device__ __forceinline__ float bf2f(unsigned short u) {
    union { unsigned u; float f; } x; x.u = ((unsigned)u) << 16; return x.f;
}
__device__ __forceinline__ float sigm_fast(float x) {
    return 1.f / (1.f + __expf(-x));
}
__device__ __forceinline__ float tanh_fast(float x) {
    float e = __expf(2.f * x);
    return 1.f - 2.f / (e + 1.f);
}

// ---------------------------------------------------------------------------
__global__ void build_x(const float* __restrict__ X_lag,
                        const float* __restrict__ X_cov,
                        float* __restrict__ x_in)
{
    int idx = blockIdx.x * 256 + threadIdx.x;      // < 30720*64
    int d = idx & 63;
    int m = idx >> 6;                               // b*120 + t
    int b = m / 120, t = m - b * 120;
    float v;
    if (d < 32) v = X_lag[((size_t)t * BATCH + b) * 32 + d];
    else        v = X_cov[((size_t)t * BATCH + b) * 32 + (d - 32)];
    x_in[idx] = v;
}

__global__ void cast_whh0(const float* __restrict__ W, unsigned short* __restrict__ o)
{
    int i = blockIdx.x * 256 + threadIdx.x;        // < 786432
    o[i] = f2bf(W[i]);
}

// Wcat1 [1536][1024]: cols 0..511 = W_hh1, cols 512..1023 = W_ih1
__global__ void cast_wcat1(const float* __restrict__ Whh, const float* __restrict__ Wih,
                           unsigned short* __restrict__ o)
{
    int i = blockIdx.x * 256 + threadIdx.x;        // < 1572864
    int row = i >> 10, c = i & 1023;
    float v = (c < 512) ? Whh[row * 512 + c] : Wih[row * 512 + (c - 512)];
    o[i] = f2bf(v);
}

__global__ void mkbias(const float* __restrict__ bih0, const float* __restrict__ bhh0,
                       const float* __restrict__ bih1, const float* __restrict__ bhh1,
                       float* __restrict__ bcomb0, float* __restrict__ bc1)
{
    int n = blockIdx.x * 256 + threadIdx.x;        // < 1536
    bcomb0[n] = bih0[n] + (n < 1024 ? bhh0[n] : 0.f);
    bc1[n]    = bih1[n] + (n < 1024 ? bhh1[n] : 0.f);
}

// ---------------------------------------------------------------------------
// Tiled f32 GEMM, bf16 TRANSPOSED write for gx0.
// ---------------------------------------------------------------------------
__global__ __launch_bounds__(256) void gemm_abt_t(
    const float* __restrict__ A, const float* __restrict__ B,
    const float* __restrict__ bias, unsigned short* __restrict__ C,
    int M, int N, int K)
{
    __shared__ float As[32][129];
    __shared__ float Bs[32][129];
    int m0 = blockIdx.x * 128;
    int n0 = blockIdx.y * 128;
    int tid = threadIdx.x;
    int tx = tid & 15, ty = tid >> 4;
    float acc[8][8] = {};
    for (int k0 = 0; k0 < K; k0 += 32) {
        #pragma unroll
        for (int i = 0; i < 16; i++) {
            int e = tid + i * 256;
            int row = e >> 5, col = e & 31;
            As[col][row] = A[(size_t)(m0 + row) * K + k0 + col];
            Bs[col][row] = B[(size_t)(n0 + row) * K + k0 + col];
        }
        __syncthreads();
        #pragma unroll
        for (int kk = 0; kk < 32; kk++) {
            float a[8], b[8];
            #pragma unroll
            for (int i = 0; i < 8; i++) a[i] = As[kk][ty + i * 16];
            #pragma unroll
            for (int j = 0; j < 8; j++) b[j] = Bs[kk][tx + j * 16];
            #pragma unroll
            for (int i = 0; i < 8; i++)
                #pragma unroll
                for (int j = 0; j < 8; j++) acc[i][j] += a[i] * b[j];
        }
        __syncthreads();
    }
    #pragma unroll
    for (int i = 0; i < 8; i++) {
        int m = m0 + ty + i * 16;
        int b = m / 120, t = m - b * 120;
        #pragma unroll
        for (int j = 0; j < 8; j++) {
            int n = n0 + tx + j * 16;
            C[((size_t)t * 256 + b) * G3 + n] = f2bf(acc[i][j] + bias[n]);
        }
    }
}

// ---------------------------------------------------------------------------
// Persistent recurrence, fence-free: h exchanged via agent-scope (L2-bypass)
// relaxed atomics; release = s_waitcnt vmcnt(0) + relaxed flag store;
// acquire = poll + control dependency (per-wave in-order vmem issue).
// 64 blocks x 512 threads: [0,32) layer0, [32,64) layer1; block owns j-tile
// jb (16 cols) for all 256 batches; weights in LDS; f32 carry in registers.
// ---------------------------------------------------------------------------
__device__ __forceinline__ bool wait_flags(const int* __restrict__ f0,
                                           const int* __restrict__ f1,
                                           int thr0, int thr1, int lane)
{
    const int* ap = (lane < 32) ? (f0 + lane * FSTRIDE)
                                : (f1 + (lane - 32) * FSTRIDE);
    int thr = (lane < 32) ? thr0 : thr1;
    for (int it = 0; it < 1000000; ++it) {
        int v = __hip_atomic_load(ap, __ATOMIC_RELAXED, __HIP_MEMORY_SCOPE_AGENT);
        if (__all(v >= thr)) return true;
        __builtin_amdgcn_s_sleep(2);
    }
    return false;   // hang-guard: proceed (results wrong, but terminates)
}

union A8 { u64 q[2]; bf16x8 v; };

__global__ __launch_bounds__(512) void gru_persist3(
    const unsigned short* __restrict__ gx0,          // [120][256][1536] bf16
    const unsigned short* __restrict__ Whh0,         // [1536][512] bf16
    const unsigned short* __restrict__ Wcat1,        // [1536][1024] bf16
    const float* __restrict__ bhh0,
    const float* __restrict__ bc1,
    const float* __restrict__ bhh1,
    u64* __restrict__ h0r,                           // [HDEPTH][256][128] u64
    u64* __restrict__ h1r,                           // [2][256][128] u64
    float* __restrict__ out0, float* __restrict__ out1,
    int* __restrict__ flag0, int* __restrict__ flag1)
{
    __shared__ unsigned short wlds[48 * 1024];       // 96 KiB (layer0 uses half)
    __shared__ unsigned short hxch[256 * 16];        // 8 KiB publish bounce
    const int tid  = threadIdx.x;
    const int wv   = tid >> 6, lane = tid & 63;
    const int l15  = lane & 15, l4 = lane >> 4;
    const int layer = blockIdx.x >> 5;
    const int jb   = blockIdx.x & 31;
    const int j    = jb * 16 + l15;
    const int b0   = wv * 32;
    const int sw   = (l15 & 7) << 3;                 // XOR swizzle (elements)

    if (!layer) {
        for (int c = tid; c < 48 * 64; c += 512) {   // stage 48x512 weights
            int lr = c >> 6, ck = c & 63;
            int eoff = ck * 8;
            int grow = ((lr >> 4) * 512) + jb * 16 + (lr & 15);
            bf16x8 v = *(const bf16x8*)(Whh0 + (size_t)grow * 512 + eoff);
            int loff = (lr * 512 + eoff) ^ ((lr & 7) << 3);
            *(bf16x8*)&wlds[loff] = v;
        }
        const float bn0 = bhh0[1024 + j];
        float carry[2][4] = {};
        __syncthreads();

        for (int t = 0; t < T_SEQ; t++) {
            wait_flags(flag0, flag1, t - 1, t - HDEPTH, lane);
            __atomic_signal_fence(__ATOMIC_SEQ_CST);

            f32x4 a0[2], a1[2], a2[2];
            #pragma unroll
            for (int u = 0; u < 2; u++) {
                a0[u] = (f32x4){0.f,0.f,0.f,0.f};
                a1[u] = (f32x4){0.f,0.f,0.f,0.f};
                a2[u] = (f32x4){0.f,0.f,0.f,0.f};
            }
            if (t > 0) {
                const u64* hp = h0r + (size_t)((t - 1) & 3) * (256 * 128);
                #pragma unroll
                for (int u = 0; u < 2; u++) {
                    u64 aq[32];
                    const u64* rowp = hp + (size_t)(b0 + u * 16 + l15) * 128 + 2 * l4;
                    #pragma unroll
                    for (int ks = 0; ks < 16; ks++) {
                        aq[2 * ks]     = __hip_atomic_load(rowp + ks * 8,     __ATOMIC_RELAXED, __HIP_MEMORY_SCOPE_AGENT);
                        aq[2 * ks + 1] = __hip_atomic_load(rowp + ks * 8 + 1, __ATOMIC_RELAXED, __HIP_MEMORY_SCOPE_AGENT);
                    }
                    #pragma unroll
                    for (int ks = 0; ks < 16; ks++) {
                        const int ko = ks * 32 + 8 * l4;
                        A8 aa; aa.q[0] = aq[2 * ks]; aa.q[1] = aq[2 * ks + 1];
                        bf16x8 B0 = *(const bf16x8*)&wlds[((l15)      * 512 + ko) ^ sw];
                        bf16x8 B1 = *(const bf16x8*)&wlds[((16 + l15) * 512 + ko) ^ sw];
                        bf16x8 B2 = *(const bf16x8*)&wlds[((32 + l15) * 512 + ko) ^ sw];
                        a0[u] = __builtin_amdgcn_mfma_f32_16x16x32_bf16(aa.v, B0, a0[u], 0, 0, 0);
                        a1[u] = __builtin_amdgcn_mfma_f32_16x16x32_bf16(aa.v, B1, a1[u], 0, 0, 0);
                        a2[u] = __builtin_amdgcn_mfma_f32_16x16x32_bf16(aa.v, B2, a2[u], 0, 0, 0);
                    }
                }
            }
            #pragma unroll
            for (int u = 0; u < 2; u++) {
                #pragma unroll
                for (int rr = 0; rr < 4; rr++) {
                    int b = b0 + u * 16 + 4 * l4 + rr;
                    const unsigned short* gp = gx0 + ((size_t)t * 256 + b) * G3 + j;
                    float r = sigm_fast(bf2f(gp[0])   + a0[u][rr]);
                    float z = sigm_fast(bf2f(gp[512]) + a1[u][rr]);
                    float n = tanh_fast(bf2f(gp[1024]) + r * (a2[u][rr] + bn0));
                    float h = (1.f - z) * n + z * carry[u][rr];
                    carry[u][rr] = h;
                    out0[(size_t)b * TS + (size_t)t * 512 + j] = h;
                    hxch[b * 16 + l15] = f2bf(h);
                }
            }
            __syncthreads();                         // hxch complete
            {
                u64* hw = h0r + (size_t)(t & 3) * (256 * 128);
                #pragma unroll
                for (int p = tid; p < 1024; p += 512) {
                    int b = p >> 2, g = p & 3;
                    u64 v = *(const u64*)&hxch[b * 16 + g * 4];
                    __hip_atomic_store(hw + (size_t)b * 128 + jb * 4 + g, v,
                                       __ATOMIC_RELAXED, __HIP_MEMORY_SCOPE_AGENT);
                }
            }
            asm volatile("s_waitcnt vmcnt(0)" ::: "memory");
            __syncthreads();                         // all waves' stores retired
            if (tid == 0)
                __hip_atomic_store(flag0 + jb * FSTRIDE, t, __ATOMIC_RELAXED,
                                   __HIP_MEMORY_SCOPE_AGENT);
        }
    } else {
        for (int c = tid; c < 48 * 128; c += 512) {  // stage 48x1024 weights
            int lr = c >> 7, ck = c & 127;
            int eoff = ck * 8;
            int grow = ((lr >> 4) * 512) + jb * 16 + (lr & 15);
            bf16x8 v = *(const bf16x8*)(Wcat1 + (size_t)grow * 1024 + eoff);
            int loff = (lr * 1024 + eoff) ^ ((lr & 7) << 3);
            *(bf16x8*)&wlds[loff] = v;
        }
        const float br = bc1[j], bz = bc1[512 + j];
        const float bnx = bc1[1024 + j], bn = bhh1[1024 + j];
        float carry[2][4] = {};
        __syncthreads();

        for (int tau = 0; tau < T_SEQ; tau++) {
            wait_flags(flag0, flag1, tau, tau - 1, lane);
            __atomic_signal_fence(__ATOMIC_SEQ_CST);

            f32x4 a0[2], a1[2], a2[2], a3[2];
            #pragma unroll
            for (int u = 0; u < 2; u++) {
                a0[u] = (f32x4){0.f,0.f,0.f,0.f};
                a1[u] = (f32x4){0.f,0.f,0.f,0.f};
                a2[u] = (f32x4){0.f,0.f,0.f,0.f};
                a3[u] = (f32x4){0.f,0.f,0.f,0.f};
            }
            if (tau > 0) {                           // h-part: h1(tau-1)
                const u64* hp = h1r + (size_t)((tau - 1) & 1) * (256 * 128);
                #pragma unroll
                for (int u = 0; u < 2; u++) {
                    u64 aq[32];
                    const u64* rowp = hp + (size_t)(b0 + u * 16 + l15) * 128 + 2 * l4;
                    #pragma unroll
                    for (int ks = 0; ks < 16; ks++) {
                        aq[2 * ks]     = __hip_atomic_load(rowp + ks * 8,     __ATOMIC_RELAXED, __HIP_MEMORY_SCOPE_AGENT);
                        aq[2 * ks + 1] = __hip_atomic_load(rowp + ks * 8 + 1, __ATOMIC_RELAXED, __HIP_MEMORY_SCOPE_AGENT);
                    }
                    #pragma unroll
                    for (int ks = 0; ks < 16; ks++) {
                        const int ko = ks * 32 + 8 * l4;
                        A8 aa; aa.q[0] = aq[2 * ks]; aa.q[1] = aq[2 * ks + 1];
                        bf16x8 B0 = *(const bf16x8*)&wlds[((l15)      * 1024 + ko) ^ sw];
                        bf16x8 B1 = *(const bf16x8*)&wlds[((16 + l15) * 1024 + ko) ^ sw];
                        bf16x8 B2 = *(const bf16x8*)&wlds[((32 + l15) * 1024 + ko) ^ sw];
                        a0[u] = __builtin_amdgcn_mfma_f32_16x16x32_bf16(aa.v, B0, a0[u], 0, 0, 0);
                        a1[u] = __builtin_amdgcn_mfma_f32_16x16x32_bf16(aa.v, B1, a1[u], 0, 0, 0);
                        a2[u] = __builtin_amdgcn_mfma_f32_16x16x32_bf16(aa.v, B2, a2[u], 0, 0, 0);
                    }
                }
            }
            {                                        // x-part: h0(tau)
                const u64* hx = h0r + (size_t)(tau & 3) * (256 * 128);
                #pragma unroll
                for (int u = 0; u < 2; u++) {
                    u64 aq[32];
                    const u64* rowp = hx + (size_t)(b0 + u * 16 + l15) * 128 + 2 * l4;
                    #pragma unroll
                    for (int ks = 0; ks < 16; ks++) {
                        aq[2 * ks]     = __hip_atomic_load(rowp + ks * 8,     __ATOMIC_RELAXED, __HIP_MEMORY_SCOPE_AGENT);
                        aq[2 * ks + 1] = __hip_atomic_load(rowp + ks * 8 + 1, __ATOMIC_RELAXED, __HIP_MEMORY_SCOPE_AGENT);
                    }
                    #pragma unroll
                    for (int ks = 0; ks < 16; ks++) {
                        const int ko = ks * 32 + 8 * l4;
                        A8 aa; aa.q[0] = aq[2 * ks]; aa.q[1] = aq[2 * ks + 1];
                        bf16x8 B0 = *(const bf16x8*)&wlds[((l15)      * 1024 + 512 + ko) ^ sw];
                        bf16x8 B1 = *(const bf16x8*)&wlds[((16 + l15) * 1024 + 512 + ko) ^ sw];
                        bf16x8 B2 = *(const bf16x8*)&wlds[((32 + l15) * 1024 + 512 + ko) ^ sw];
                        a0[u] = __builtin_amdgcn_mfma_f32_16x16x32_bf16(aa.v, B0, a0[u], 0, 0, 0);
                        a1[u] = __builtin_amdgcn_mfma_f32_16x16x32_bf16(aa.v, B1, a1[u], 0, 0, 0);
                        a3[u] = __builtin_amdgcn_mfma_f32_16x16x32_bf16(aa.v, B2, a3[u], 0, 0, 0);
                    }
                }
            }
            #pragma unroll
            for (int u = 0; u < 2; u++) {
                #pragma unroll
                for (int rr = 0; rr < 4; rr++) {
                    int b = b0 + u * 16 + 4 * l4 + rr;
                    float r = sigm_fast(a0[u][rr] + br);
                    float z = sigm_fast(a1[u][rr] + bz);
                    float n = tanh_fast(a3[u][rr] + bnx + r * (a2[u][rr] + bn));
                    float h = (1.f - z) * n + z * carry[u][rr];
                    carry[u][rr] = h;
                    out1[(size_t)b * TS + (size_t)tau * 512 + j] = h;
                    hxch[b * 16 + l15] = f2bf(h);
                }
            }
            __syncthreads();
            {
                u64* hw = h1r + (size_t)(tau & 1) * (256 * 128);
                #pragma unroll
                for (int p = tid; p < 1024; p += 512) {
                    int b = p >> 2, g = p & 3;
                    u64 v = *(const u64*)&hxch[b * 16 + g * 4];
                    __hip_atomic_store(hw + (size_t)b * 128 + jb * 4 + g, v,
                                       __ATOMIC_RELAXED, __HIP_MEMORY_SCOPE_AGENT);
                }
            }
            asm volatile("s_waitcnt vmcnt(0)" ::: "memory");
            __syncthreads();
            if (tid == 0)
                __hip_atomic_store(flag1 + jb * FSTRIDE, tau, __ATOMIC_RELAXED,
                                   __HIP_MEMORY_SCOPE_AGENT);
        }
    }
}

// ---------------------------------------------------------------------------
// z partials: 960 blocks = (t, half, c-quarter of 128).   [verified r4-r6]
// ---------------------------------------------------------------------------
__global__ __launch_bounds__(256) void zpart_kernel(
    const float* __restrict__ out, const float* __restrict__ Gw,
    float* __restrict__ zp)
{
    __shared__ float Os[128][33];
    __shared__ float Gs[128][33];
    int bk = blockIdx.x;
    int t = bk >> 3, half = (bk >> 2) & 1, cq = bk & 3;
    int tid = threadIdx.x;
    int tx = tid & 15, ty = tid >> 4;
    float acc[8][8] = {};
    int cbase = cq * 128;
    for (int c0 = cbase; c0 < cbase + 128; c0 += 32) {
        #pragma unroll
        for (int i = 0; i < 16; i++) {
            int e = tid + i * 256;
            int row = e >> 5, col = e & 31;
            Os[row][col] = out[(size_t)(row + half * 128) * TS + (size_t)t * 512 + c0 + col];
            float v = 0.f;
            if (row < 120)
                v = Gw[(size_t)row * KGATE + (size_t)t * 1024 + half * 512 + c0 + col];
            Gs[row][col] = v;
        }
        __syncthreads();
        #pragma unroll
        for (int kk = 0; kk < 32; kk++) {
            float a[8], g[8];
            #pragma unroll
            for (int i = 0; i < 8; i++) a[i] = Os[ty + i * 16][kk];
            #pragma unroll
            for (int j = 0; j < 8; j++) g[j] = Gs[tx + j * 16][kk];
            #pragma unroll
            for (int i = 0; i < 8; i++)
                #pragma unroll
                for (int j = 0; j < 8; j++) acc[i][j] += a[i] * g[j];
        }
        __syncthreads();
    }
    float* zb = zp + (size_t)bk * (128 * 120);
    #pragma unroll
    for (int i = 0; i < 8; i++) {
        int ii = ty + i * 16;
        #pragma unroll
        for (int j = 0; j < 8; j++) {
            int r = tx + j * 16;
            if (r < 120) zb[ii * 120 + r] = acc[i][j];
        }
    }
}

__global__ void zreduce(const float* __restrict__ zp,
                        const float* __restrict__ gate_b_l,
                        float* __restrict__ z)
{
    int idx = blockIdx.x * 256 + threadIdx.x;
    if (idx >= 128 * 120) return;
    float s = 0.f;
    for (int c = 0; c < 960; c++) s += zp[(size_t)c * (128 * 120) + idx];
    z[idx] = s + gate_b_l[idx % 120];
}

__global__ __launch_bounds__(128) void bn_col(
    const float* __restrict__ z, const float* __restrict__ gamma,
    const float* __restrict__ beta, float* __restrict__ wm)
{
    int r = blockIdx.x, i = threadIdx.x;
    __shared__ float sh[2];
    float v = z[i * 120 + r];
    float s = v;
    for (int o = 32; o > 0; o >>= 1) s += __shfl_down(s, o);
    if ((i & 63) == 0) sh[i >> 6] = s;
    __syncthreads();
    float m = (sh[0] + sh[1]) * (1.f / 128.f);
    __syncthreads();
    float d = (v - m) * (v - m);
    for (int o = 32; o > 0; o >>= 1) d += __shfl_down(d, o);
    if ((i & 63) == 0) sh[i >> 6] = d;
    __syncthreads();
    float var = (sh[0] + sh[1]) * (1.f / 128.f);
    float w = 1.f / (1.f + expf(-(gamma[r] * (v - m) / sqrtf(var + 1e-5f) + beta[r])));
    __syncthreads();
    float ws_ = w;
    for (int o = 32; o > 0; o >>= 1) ws_ += __shfl_down(ws_, o);
    if ((i & 63) == 0) sh[i >> 6] = ws_;
    __syncthreads();
    if (i == 0) wm[r] = (sh[0] + sh[1]) * (1.f / 128.f);
}

__global__ __launch_bounds__(128) void softmax120(
    const float* __restrict__ wm, float* __restrict__ g_out,
    float* __restrict__ g_ws)
{
    int i = threadIdx.x;
    __shared__ float sh[2];
    float v = (i < 120) ? wm[i] : -1e30f;
    float m = v;
    for (int o = 32; o > 0; o >>= 1) m = fmaxf(m, __shfl_down(m, o));
    if ((i & 63) == 0) sh[i >> 6] = m;
    __syncthreads();
    float mx = fmaxf(sh[0], sh[1]);
    float e = (i < 120) ? expf(v - mx) : 0.f;
    __syncthreads();
    float se = e;
    for (int o = 32; o > 0; o >>= 1) se += __shfl_down(se, o);
    if ((i & 63) == 0) sh[i >> 6] = se;
    __syncthreads();
    float sum = sh[0] + sh[1];
    if (i < 120) { float g = e / sum; g_out[i] = g; g_ws[i] = g; }
}

__global__ void halfmeans(const float* __restrict__ out,
                          float* __restrict__ ms, float* __restrict__ mt)
{
    int idx = blockIdx.x * 256 + threadIdx.x;
    int half = idx >= TS;
    int tc = idx - half * TS;
    const float* base = out + (size_t)(half * 128) * TS + tc;
    float s = 0.f;
    for (int i = 0; i < 128; i++) s += base[(size_t)i * TS];
    s *= (1.f / 128.f);
    if (half) mt[tc] = s; else ms[tc] = s;
}

__global__ __launch_bounds__(512) void transfer_part(
    const float* __restrict__ ms, const float* __restrict__ mt,
    const float* __restrict__ gw, const int* __restrict__ lenw,
    float* __restrict__ part)
{
    int t = blockIdx.x, c = threadIdx.x;
    int lw = lenw[0];
    int j0 = t - lw; if (j0 < 0) j0 = 0;
    int j1 = t + lw; if (j1 > 119) j1 = 119;
    float m_c = ms[(size_t)t * 512 + c];
    float acc = 0.f;
    for (int j = j0; j <= j1; j++) {
        float d = m_c - mt[(size_t)j * 512 + c];
        acc += d * d;
    }
    for (int o = 32; o > 0; o >>= 1) acc += __shfl_down(acc, o);
    __shared__ float sh[8];
    if ((c & 63) == 0) sh[c >> 6] = acc;
    __syncthreads();
    if (c == 0) {
        float s = 0.f;
        #pragma unroll
        for (int k = 0; k < 8; k++) s += sh[k];
        part[t] = gw[t] * s;
    }
}

__global__ __launch_bounds__(256) void yhat_kernel(
    const float* __restrict__ out1, const float* __restrict__ y,
    const float* __restrict__ fcW, const float* __restrict__ fcb,
    int dsl, float* __restrict__ dout, float* __restrict__ lp_rows)
{
    int wid = blockIdx.x * 4 + (threadIdx.x >> 6);   // 0..dsl*256-1
    int lane = threadIdx.x & 63;
    int tt = wid >> 8, b = wid & 255;
    int t = T_SEQ - dsl + tt;
    const float* row = out1 + (size_t)b * TS + (size_t)t * 512;
    float s = 0.f;
    #pragma unroll
    for (int k = 0; k < 8; k++) s += row[lane + 64 * k] * fcW[lane + 64 * k];
    for (int o = 32; o > 0; o >>= 1) s += __shfl_down(s, o);
    if (lane == 0) {
        float loc = s + fcb[0];
        float sp = fmaxf(loc, 0.f) + log1pf(expf(-fabsf(loc)));
        float scale = sp + 1e-6f;
        dout[2 + tt * 256 + b] = loc;
        dout[2 + dsl * 256 + tt * 256 + b] = scale;
        float yt = y[(size_t)t * 256 + b];
        float u = (yt - loc) / scale;
        lp_rows[wid] = -0.5f * u * u - logf(scale) - 0.91893853320467274f;
    }
}

__global__ __launch_bounds__(64) void finalize(
    const float* __restrict__ lp_rows, const float* __restrict__ part0,
    const float* __restrict__ part1, float* __restrict__ dout, int n_lp)
{
    int i = threadIdx.x;
    float s = 0.f;
    for (int k = i; k < n_lp; k += 64) s += lp_rows[k];
    for (int o = 32; o > 0; o >>= 1) s += __shfl_down(s, o);
    float tr = 0.f;
    for (int k = i; k < 120; k += 64) tr += part0[k] + part1[k];
    for (int o = 32; o > 0; o >>= 1) tr += __shfl_down(tr, o);
    if (i == 0) {
        float ly = -s / (float)n_lp;
        dout[1] = ly;
        dout[0] = ly + tr;
    }
}

// ---------------------------------------------------------------------------
extern "C" void kernel_launch(void* const* d_in, const int* in_sizes, int n_in,
                              void* d_out, int out_size, void* d_ws, size_t ws_size,
                              hipStream_t stream)
{
    const float* X_cov  = (const float*)d_in[1];
    const float* X_lag  = (const float*)d_in[2];
    const float* y      = (const float*)d_in[3];
    const int*   lenw   = (const int*)d_in[5];
    const float* W_ih0  = (const float*)d_in[6];
    const float* W_hh0  = (const float*)d_in[7];
    const float* b_ih0  = (const float*)d_in[8];
    const float* b_hh0  = (const float*)d_in[9];
    const float* W_ih1  = (const float*)d_in[10];
    const float* W_hh1  = (const float*)d_in[11];
    const float* b_ih1  = (const float*)d_in[12];
    const float* b_hh1  = (const float*)d_in[13];
    const float* gate_W = (const float*)d_in[14];
    const float* gate_b = (const float*)d_in[15];
    const float* bn_g   = (const float*)d_in[16];
    const float* bn_b   = (const float*)d_in[17];
    const float* fc_W   = (const float*)d_in[18];
    const float* fc_b   = (const float*)d_in[19];
    float* dout = (float*)d_out;
    float* ws   = (float*)d_ws;

    // workspace layout (float offsets). Aliases are time-disjoint:
    //  - zp aliases gx0 (gx0 dead after gru_persist3)
    //  - lp_rows aliases x_in (dead after gemm_abt_t)
    float* x_in    = ws;                          // 1,966,080
    unsigned short* gx0bf = (unsigned short*)(ws + 1966080);      // 47,185,920 ush
    float* out0    = ws + 25559040;               // 15,728,640
    float* out1    = ws + 41287680;               // 15,728,640
    unsigned short* Whh0bf  = (unsigned short*)(ws + 57016320);   // 786,432 ush
    unsigned short* Wcat1bf = (unsigned short*)(ws + 57409536);   // 1,572,864 ush
    u64* h0r       = (u64*)(ws + 58195968);       // 4*256*128 u64
    u64* h1r       = (u64*)(ws + 58458112);       // 2*256*128 u64
    float* zmat    = ws + 58589184;               // 15,360
    float* wm      = ws + 58604544;               // 120
    float* gw_ws   = ws + 58604664;               // 240
    float* msb     = ws + 58604904;               // 61,440
    float* mtb     = ws + 58666344;               // 61,440
    float* part    = ws + 58727784;               // 240
    float* bcomb0  = ws + 58728024;               // 1536
    float* bc1     = ws + 58729560;               // 1536
    int*   flags   = (int*)(ws + 58731096);       // 1024 ints (2x32 strided)
    float* zp      = ws + 1966080;                // 14,745,600 (alias of gx0)
    float* lp_rows = x_in;                        // dsl*256 (alias)
    int* flag0 = flags;
    int* flag1 = flags + 32 * FSTRIDE;

    int dsl = (out_size - 2 - 2 * T_SEQ) / (2 * BATCH);   // = 24

    build_x<<<dim3(7680), 256, 0, stream>>>(X_lag, X_cov, x_in);
    cast_whh0<<<dim3(3072), 256, 0, stream>>>(W_hh0, Whh0bf);
    cast_wcat1<<<dim3(6144), 256, 0, stream>>>(W_hh1, W_ih1, Wcat1bf);
    mkbias<<<dim3(6), 256, 0, stream>>>(b_ih0, b_hh0, b_ih1, b_hh1, bcomb0, bc1);
    hipMemsetAsync(flags, 0xFF, 1024 * sizeof(int), stream);   // flags = -1

    gemm_abt_t<<<dim3(240, 12), 256, 0, stream>>>(x_in, W_ih0, bcomb0, gx0bf,
                                                  MROWS, G3, 64);

    gru_persist3<<<dim3(64), 512, 0, stream>>>(gx0bf, Whh0bf, Wcat1bf,
                                               b_hh0, bc1, b_hh1,
                                               h0r, h1r, out0, out1,
                                               flag0, flag1);

    for (int l = 0; l < 2; l++) {
        const float* o = l ? out1 : out0;
        zpart_kernel<<<960, 256, 0, stream>>>(o, gate_W + (size_t)l * 120 * KGATE, zp);
        zreduce<<<60, 256, 0, stream>>>(zp, gate_b + l * 120, zmat);
        bn_col<<<120, 128, 0, stream>>>(zmat, bn_g + l * 120, bn_b + l * 120, wm);
        softmax120<<<1, 128, 0, stream>>>(wm, dout + 2 + 2 * dsl * 256 + l * 120,
                                          gw_ws + l * 120);
        halfmeans<<<480, 256, 0, stream>>>(o, msb, mtb);
        transfer_part<<<120, 512, 0, stream>>>(msb, mtb, gw_ws + l * 120, lenw,
                                               part + l * 120);
    }

    yhat_kernel<<<dsl * 64, 256, 0, stream>>>(out1, y, fc_W, fc_b, dsl, dout, lp_rows);
    finalize<<<1, 64, 0, stream>>>(lp_rows, part, part + 120, dout, dsl * 256);
}

// Round 8
// 1897.715 us; speedup vs baseline: 2.9988x; 2.1980x over previous
//
#include <hip/hip_runtime.h>
#include <math.h>

#define T_SEQ 120
#define BATCH 256
#define HID   512
#define G3    1536            // 3*HID
#define MROWS (BATCH*T_SEQ)   // 30720
#define TS    (T_SEQ*HID)     // 61440, row stride per batch in out buffers
#define KGATE 122880          // T_SEQ*2*HID
#define FSTRIDE 16            // flag stride (ints) -> one flag per 64B line
#define NEGINF (-2147483647)

typedef __attribute__((ext_vector_type(8))) short bf16x8;
typedef __attribute__((ext_vector_type(4))) float f32x4;

__device__ __forceinline__ unsigned short f2bf(float f) {
    union { float f; unsigned u; } x; x.f = f;
    unsigned r = x.u + 0x7fffu + ((x.u >> 16) & 1u);   // RNE
    return (unsigned short)(r >> 16);
}
__device__ __forceinline__ float bf2f(unsigned short u) {
    union { unsigned u; float f; } x; x.u = ((unsigned)u) << 16; return x.f;
}
__device__ __forceinline__ float sigm_fast(float x) {
    return 1.f / (1.f + __expf(-x));
}
__device__ __forceinline__ float tanh_fast(float x) {
    float e = __expf(2.f * x);
    return 1.f - 2.f / (e + 1.f);
}

// ---------------------------------------------------------------------------
__global__ void build_x(const float* __restrict__ X_lag,
                        const float* __restrict__ X_cov,
                        float* __restrict__ x_in)
{
    int idx = blockIdx.x * 256 + threadIdx.x;      // < 30720*64
    int d = idx & 63;
    int m = idx >> 6;                               // b*120 + t
    int b = m / 120, t = m - b * 120;
    float v;
    if (d < 32) v = X_lag[((size_t)t * BATCH + b) * 32 + d];
    else        v = X_cov[((size_t)t * BATCH + b) * 32 + (d - 32)];
    x_in[idx] = v;
}

__global__ void cast_whh0(const float* __restrict__ W, unsigned short* __restrict__ o)
{
    int i = blockIdx.x * 256 + threadIdx.x;        // < 786432
    o[i] = f2bf(W[i]);
}

// Wcat1 [1536][1024]: cols 0..511 = W_hh1, cols 512..1023 = W_ih1
__global__ void cast_wcat1(const float* __restrict__ Whh, const float* __restrict__ Wih,
                           unsigned short* __restrict__ o)
{
    int i = blockIdx.x * 256 + threadIdx.x;        // < 1572864
    int row = i >> 10, c = i & 1023;
    float v = (c < 512) ? Whh[row * 512 + c] : Wih[row * 512 + (c - 512)];
    o[i] = f2bf(v);
}

__global__ void mkbias(const float* __restrict__ bih0, const float* __restrict__ bhh0,
                       const float* __restrict__ bih1, const float* __restrict__ bhh1,
                       float* __restrict__ bcomb0, float* __restrict__ bc1)
{
    int n = blockIdx.x * 256 + threadIdx.x;        // < 1536
    bcomb0[n] = bih0[n] + (n < 1024 ? bhh0[n] : 0.f);
    bc1[n]    = bih1[n] + (n < 1024 ? bhh1[n] : 0.f);
}

// ---------------------------------------------------------------------------
// Tiled f32 GEMM, bf16 TRANSPOSED write for gx0.   [verified r6/r7]
// ---------------------------------------------------------------------------
__global__ __launch_bounds__(256) void gemm_abt_t(
    const float* __restrict__ A, const float* __restrict__ B,
    const float* __restrict__ bias, unsigned short* __restrict__ C,
    int M, int N, int K)
{
    __shared__ float As[32][129];
    __shared__ float Bs[32][129];
    int m0 = blockIdx.x * 128;
    int n0 = blockIdx.y * 128;
    int tid = threadIdx.x;
    int tx = tid & 15, ty = tid >> 4;
    float acc[8][8] = {};
    for (int k0 = 0; k0 < K; k0 += 32) {
        #pragma unroll
        for (int i = 0; i < 16; i++) {
            int e = tid + i * 256;
            int row = e >> 5, col = e & 31;
            As[col][row] = A[(size_t)(m0 + row) * K + k0 + col];
            Bs[col][row] = B[(size_t)(n0 + row) * K + k0 + col];
        }
        __syncthreads();
        #pragma unroll
        for (int kk = 0; kk < 32; kk++) {
            float a[8], b[8];
            #pragma unroll
            for (int i = 0; i < 8; i++) a[i] = As[kk][ty + i * 16];
            #pragma unroll
            for (int j = 0; j < 8; j++) b[j] = Bs[kk][tx + j * 16];
            #pragma unroll
            for (int i = 0; i < 8; i++)
                #pragma unroll
                for (int j = 0; j < 8; j++) acc[i][j] += a[i] * b[j];
        }
        __syncthreads();
    }
    #pragma unroll
    for (int i = 0; i < 8; i++) {
        int m = m0 + ty + i * 16;
        int b = m / 120, t = m - b * 120;
        #pragma unroll
        for (int j = 0; j < 8; j++) {
            int n = n0 + tx + j * 16;
            C[((size_t)t * 256 + b) * G3 + n] = f2bf(acc[i][j] + bias[n]);
        }
    }
}

// ---------------------------------------------------------------------------
// XCD-partitioned persistent recurrence.
// Each physical XCD (self-discovered via HW_REG_XCC_ID) owns batches
// [xcd*32, xcd*32+32). Its 32 resident blocks claim roles via atomicAdd:
// roles 0-15 = layer0 j-blocks (32 cols), 16-31 = layer1 j-blocks.
// h state IS the bf16 out buffer (fresh address every step -> no stale
// caching possible). Producer: write-through stores + vmcnt(0) + agent flag.
// Consumer: poll flag (L3) then plain cached loads (same-XCD L2 hit).
// Layer0 never waits on layer1. Bounded spin = hang guard.
// ---------------------------------------------------------------------------
__device__ __forceinline__ bool wait2(const int* __restrict__ f0b,
                                      const int* __restrict__ f1b,
                                      int thr0, int thr1, int lane)
{
    const int* ap; int thr;
    if (lane < 16)      { ap = f0b + lane * FSTRIDE;        thr = thr0; }
    else if (lane < 32) { ap = f1b + (lane - 16) * FSTRIDE; thr = thr1; }
    else                { ap = f0b;                         thr = NEGINF; }
    for (int it = 0; it < 50000; ++it) {
        int v = __hip_atomic_load(ap, __ATOMIC_RELAXED, __HIP_MEMORY_SCOPE_AGENT);
        if (__all(v >= thr)) return true;
        __builtin_amdgcn_s_sleep(1);
    }
    return false;
}

__global__ __launch_bounds__(256) void gru_xcd(
    const unsigned short* __restrict__ gx0,          // [120][256][1536] bf16
    const unsigned short* __restrict__ Whh0,         // [1536][512] bf16
    const unsigned short* __restrict__ Wcat1,        // [1536][1024] bf16
    const float* __restrict__ bhh0,
    const float* __restrict__ bc1,
    const float* __restrict__ bhh1,
    unsigned short* __restrict__ out0,               // [256][120][512] bf16
    unsigned short* __restrict__ out1,               // [256][120][512] bf16
    int* __restrict__ flags,                         // [2][8][16] x FSTRIDE
    int* __restrict__ rolecnt)                       // [8] (x16 pad)
{
    __shared__ unsigned short wlds[96 * 520];        // ~97.5 KiB
    __shared__ int role_s;

    int xcd;
    asm("s_getreg_b32 %0, hwreg(20, 0, 32)" : "=s"(xcd));   // HW_REG_XCC_ID
    xcd &= 7;
    if (threadIdx.x == 0) role_s = atomicAdd(&rolecnt[xcd * 16], 1);
    __syncthreads();
    const int role = role_s;
    if (role >= 32) return;

    const int layer = role >> 4;
    const int jb    = role & 15;
    const int j0    = jb * 32;
    const int tid   = threadIdx.x;
    const int w     = tid >> 6, lane = tid & 63;
    const int l15   = lane & 15, l4 = lane >> 4;
    const int jt    = w & 1, bt = w >> 1;
    const int jloc  = jt * 16 + l15;                 // 0..31
    const int j     = j0 + jloc;
    const int bloc0 = bt * 16;                       // 0 or 16
    const int bg0   = xcd * 32;                      // global batch base

    // stage hh-part weights (96 rows x 512) into LDS, padded stride 520
    {
        const unsigned short* Wsrc = layer ? Wcat1 : Whh0;
        const int wstr = layer ? 1024 : 512;
        for (int c = tid; c < 96 * 64; c += 256) {
            int lr = c >> 6, ck = c & 63;
            int grow = (lr >> 5) * 512 + j0 + (lr & 31);
            bf16x8 v = *(const bf16x8*)(Wsrc + (size_t)grow * wstr + ck * 8);
            *(bf16x8*)&wlds[lr * 520 + ck * 8] = v;
        }
    }
    float bn_, br_ = 0.f, bz_ = 0.f, bnx_ = 0.f;
    if (layer) { br_ = bc1[j]; bz_ = bc1[512 + j]; bnx_ = bc1[1024 + j]; bn_ = bhh1[1024 + j]; }
    else       { bn_ = bhh0[1024 + j]; }
    float carry[4] = {0.f, 0.f, 0.f, 0.f};

    const int* f0b = flags + (0 * 8 + xcd) * 16 * FSTRIDE;
    const int* f1b = flags + (1 * 8 + xcd) * 16 * FSTRIDE;
    int* myf = flags + ((layer * 8 + xcd) * 16 + jb) * FSTRIDE;
    __syncthreads();

    for (int t = 0; t < T_SEQ; t++) {
        bool ok = layer ? wait2(f0b, f1b, t, t - 1, lane)
                        : wait2(f0b, f1b, t - 1, NEGINF, lane);
        if (!ok) break;                              // hang guard

        f32x4 a0 = {0,0,0,0}, a1 = {0,0,0,0}, a2 = {0,0,0,0}, a3 = {0,0,0,0};
        if (t > 0) {                                 // hh-part: own layer h(t-1)
            const unsigned short* hp = layer ? out1 : out0;
            #pragma unroll
            for (int ks = 0; ks < 16; ks++) {
                const int ko = ks * 32 + 8 * l4;
                bf16x8 A = *(const bf16x8*)(hp + ((size_t)(bg0 + bloc0 + l15) * T_SEQ + (t - 1)) * 512 + ko);
                bf16x8 B0 = *(const bf16x8*)&wlds[(0 * 32 + jloc) * 520 + ko];
                bf16x8 B1 = *(const bf16x8*)&wlds[(1 * 32 + jloc) * 520 + ko];
                bf16x8 B2 = *(const bf16x8*)&wlds[(2 * 32 + jloc) * 520 + ko];
                a0 = __builtin_amdgcn_mfma_f32_16x16x32_bf16(A, B0, a0, 0, 0, 0);
                a1 = __builtin_amdgcn_mfma_f32_16x16x32_bf16(A, B1, a1, 0, 0, 0);
                a2 = __builtin_amdgcn_mfma_f32_16x16x32_bf16(A, B2, a2, 0, 0, 0);
            }
        }
        if (layer) {                                 // x-part: out0(t), W cols 512+
            #pragma unroll
            for (int ks = 0; ks < 16; ks++) {
                const int ko = ks * 32 + 8 * l4;
                bf16x8 A = *(const bf16x8*)(out0 + ((size_t)(bg0 + bloc0 + l15) * T_SEQ + t) * 512 + ko);
                const unsigned short* wb = Wcat1 + (size_t)j * 1024 + 512 + ko;
                bf16x8 B0 = *(const bf16x8*)(wb);
                bf16x8 B1 = *(const bf16x8*)(wb + 512 * 1024);
                bf16x8 B2 = *(const bf16x8*)(wb + 1024 * 1024);
                a0 = __builtin_amdgcn_mfma_f32_16x16x32_bf16(A, B0, a0, 0, 0, 0);
                a1 = __builtin_amdgcn_mfma_f32_16x16x32_bf16(A, B1, a1, 0, 0, 0);
                a3 = __builtin_amdgcn_mfma_f32_16x16x32_bf16(A, B2, a3, 0, 0, 0);
            }
        }
        unsigned short* op = layer ? out1 : out0;
        #pragma unroll
        for (int rr = 0; rr < 4; rr++) {
            int b = bg0 + bloc0 + 4 * l4 + rr;
            float pr, pz, pnx;
            if (!layer) {
                const unsigned short* gp = gx0 + ((size_t)t * 256 + b) * G3 + j;
                pr  = bf2f(gp[0])    + a0[rr];
                pz  = bf2f(gp[512])  + a1[rr];
                pnx = bf2f(gp[1024]);
            } else {
                pr = a0[rr] + br_; pz = a1[rr] + bz_; pnx = a3[rr] + bnx_;
            }
            float r = sigm_fast(pr);
            float z = sigm_fast(pz);
            float n = tanh_fast(pnx + r * (a2[rr] + bn_));
            float h = (1.f - z) * n + z * carry[rr];
            carry[rr] = h;
            op[((size_t)b * T_SEQ + t) * 512 + j] = f2bf(h);
        }
        asm volatile("s_waitcnt vmcnt(0)" ::: "memory");  // stores in L2
        __syncthreads();
        if (tid == 0)
            __hip_atomic_store(myf, t, __ATOMIC_RELAXED, __HIP_MEMORY_SCOPE_AGENT);
    }
}

// ---------------------------------------------------------------------------
// z partials (bf16 out reader): 960 blocks = (t, half, c-quarter).
// ---------------------------------------------------------------------------
__global__ __launch_bounds__(256) void zpart_kernel(
    const unsigned short* __restrict__ out, const float* __restrict__ Gw,
    float* __restrict__ zp)
{
    __shared__ float Os[128][33];
    __shared__ float Gs[128][33];
    int bk = blockIdx.x;
    int t = bk >> 3, half = (bk >> 2) & 1, cq = bk & 3;
    int tid = threadIdx.x;
    int tx = tid & 15, ty = tid >> 4;
    float acc[8][8] = {};
    int cbase = cq * 128;
    for (int c0 = cbase; c0 < cbase + 128; c0 += 32) {
        #pragma unroll
        for (int i = 0; i < 16; i++) {
            int e = tid + i * 256;
            int row = e >> 5, col = e & 31;
            Os[row][col] = bf2f(out[((size_t)(row + half * 128) * T_SEQ + t) * 512 + c0 + col]);
            float v = 0.f;
            if (row < 120)
                v = Gw[(size_t)row * KGATE + (size_t)t * 1024 + half * 512 + c0 + col];
            Gs[row][col] = v;
        }
        __syncthreads();
        #pragma unroll
        for (int kk = 0; kk < 32; kk++) {
            float a[8], g[8];
            #pragma unroll
            for (int i = 0; i < 8; i++) a[i] = Os[ty + i * 16][kk];
            #pragma unroll
            for (int j = 0; j < 8; j++) g[j] = Gs[tx + j * 16][kk];
            #pragma unroll
            for (int i = 0; i < 8; i++)
                #pragma unroll
                for (int j = 0; j < 8; j++) acc[i][j] += a[i] * g[j];
        }
        __syncthreads();
    }
    float* zb = zp + (size_t)bk * (128 * 120);
    #pragma unroll
    for (int i = 0; i < 8; i++) {
        int ii = ty + i * 16;
        #pragma unroll
        for (int j = 0; j < 8; j++) {
            int r = tx + j * 16;
            if (r < 120) zb[ii * 120 + r] = acc[i][j];
        }
    }
}

__global__ void zreduce(const float* __restrict__ zp,
                        const float* __restrict__ gate_b_l,
                        float* __restrict__ z)
{
    int idx = blockIdx.x * 256 + threadIdx.x;
    if (idx >= 128 * 120) return;
    float s = 0.f;
    for (int c = 0; c < 960; c++) s += zp[(size_t)c * (128 * 120) + idx];
    z[idx] = s + gate_b_l[idx % 120];
}

__global__ __launch_bounds__(128) void bn_col(
    const float* __restrict__ z, const float* __restrict__ gamma,
    const float* __restrict__ beta, float* __restrict__ wm)
{
    int r = blockIdx.x, i = threadIdx.x;
    __shared__ float sh[2];
    float v = z[i * 120 + r];
    float s = v;
    for (int o = 32; o > 0; o >>= 1) s += __shfl_down(s, o);
    if ((i & 63) == 0) sh[i >> 6] = s;
    __syncthreads();
    float m = (sh[0] + sh[1]) * (1.f / 128.f);
    __syncthreads();
    float d = (v - m) * (v - m);
    for (int o = 32; o > 0; o >>= 1) d += __shfl_down(d, o);
    if ((i & 63) == 0) sh[i >> 6] = d;
    __syncthreads();
    float var = (sh[0] + sh[1]) * (1.f / 128.f);
    float w = 1.f / (1.f + expf(-(gamma[r] * (v - m) / sqrtf(var + 1e-5f) + beta[r])));
    __syncthreads();
    float ws_ = w;
    for (int o = 32; o > 0; o >>= 1) ws_ += __shfl_down(ws_, o);
    if ((i & 63) == 0) sh[i >> 6] = ws_;
    __syncthreads();
    if (i == 0) wm[r] = (sh[0] + sh[1]) * (1.f / 128.f);
}

__global__ __launch_bounds__(128) void softmax120(
    const float* __restrict__ wm, float* __restrict__ g_out,
    float* __restrict__ g_ws)
{
    int i = threadIdx.x;
    __shared__ float sh[2];
    float v = (i < 120) ? wm[i] : -1e30f;
    float m = v;
    for (int o = 32; o > 0; o >>= 1) m = fmaxf(m, __shfl_down(m, o));
    if ((i & 63) == 0) sh[i >> 6] = m;
    __syncthreads();
    float mx = fmaxf(sh[0], sh[1]);
    float e = (i < 120) ? expf(v - mx) : 0.f;
    __syncthreads();
    float se = e;
    for (int o = 32; o > 0; o >>= 1) se += __shfl_down(se, o);
    if ((i & 63) == 0) sh[i >> 6] = se;
    __syncthreads();
    float sum = sh[0] + sh[1];
    if (i < 120) { float g = e / sum; g_out[i] = g; g_ws[i] = g; }
}

__global__ void halfmeans(const unsigned short* __restrict__ out,
                          float* __restrict__ ms, float* __restrict__ mt)
{
    int idx = blockIdx.x * 256 + threadIdx.x;
    int half = idx >= TS;
    int tc = idx - half * TS;
    const unsigned short* base = out + (size_t)(half * 128) * TS + tc;
    float s = 0.f;
    for (int i = 0; i < 128; i++) s += bf2f(base[(size_t)i * TS]);
    s *= (1.f / 128.f);
    if (half) mt[tc] = s; else ms[tc] = s;
}

__global__ __launch_bounds__(512) void transfer_part(
    const float* __restrict__ ms, const float* __restrict__ mt,
    const float* __restrict__ gw, const int* __restrict__ lenw,
    float* __restrict__ part)
{
    int t = blockIdx.x, c = threadIdx.x;
    int lw = lenw[0];
    int j0 = t - lw; if (j0 < 0) j0 = 0;
    int j1 = t + lw; if (j1 > 119) j1 = 119;
    float m_c = ms[(size_t)t * 512 + c];
    float acc = 0.f;
    for (int j = j0; j <= j1; j++) {
        float d = m_c - mt[(size_t)j * 512 + c];
        acc += d * d;
    }
    for (int o = 32; o > 0; o >>= 1) acc += __shfl_down(acc, o);
    __shared__ float sh[8];
    if ((c & 63) == 0) sh[c >> 6] = acc;
    __syncthreads();
    if (c == 0) {
        float s = 0.f;
        #pragma unroll
        for (int k = 0; k < 8; k++) s += sh[k];
        part[t] = gw[t] * s;
    }
}

__global__ __launch_bounds__(256) void yhat_kernel(
    const unsigned short* __restrict__ out1, const float* __restrict__ y,
    const float* __restrict__ fcW, const float* __restrict__ fcb,
    int dsl, float* __restrict__ dout, float* __restrict__ lp_rows)
{
    int wid = blockIdx.x * 4 + (threadIdx.x >> 6);   // 0..dsl*256-1
    int lane = threadIdx.x & 63;
    int tt = wid >> 8, b = wid & 255;
    int t = T_SEQ - dsl + tt;
    const unsigned short* row = out1 + ((size_t)b * T_SEQ + t) * 512;
    float s = 0.f;
    #pragma unroll
    for (int k = 0; k < 8; k++) s += bf2f(row[lane + 64 * k]) * fcW[lane + 64 * k];
    for (int o = 32; o > 0; o >>= 1) s += __shfl_down(s, o);
    if (lane == 0) {
        float loc = s + fcb[0];
        float sp = fmaxf(loc, 0.f) + log1pf(expf(-fabsf(loc)));
        float scale = sp + 1e-6f;
        dout[2 + tt * 256 + b] = loc;
        dout[2 + dsl * 256 + tt * 256 + b] = scale;
        float yt = y[(size_t)t * 256 + b];
        float u = (yt - loc) / scale;
        lp_rows[wid] = -0.5f * u * u - logf(scale) - 0.91893853320467274f;
    }
}

__global__ __launch_bounds__(64) void finalize(
    const float* __restrict__ lp_rows, const float* __restrict__ part0,
    const float* __restrict__ part1, float* __restrict__ dout, int n_lp)
{
    int i = threadIdx.x;
    float s = 0.f;
    for (int k = i; k < n_lp; k += 64) s += lp_rows[k];
    for (int o = 32; o > 0; o >>= 1) s += __shfl_down(s, o);
    float tr = 0.f;
    for (int k = i; k < 120; k += 64) tr += part0[k] + part1[k];
    for (int o = 32; o > 0; o >>= 1) tr += __shfl_down(tr, o);
    if (i == 0) {
        float ly = -s / (float)n_lp;
        dout[1] = ly;
        dout[0] = ly + tr;
    }
}

// ---------------------------------------------------------------------------
extern "C" void kernel_launch(void* const* d_in, const int* in_sizes, int n_in,
                              void* d_out, int out_size, void* d_ws, size_t ws_size,
                              hipStream_t stream)
{
    const float* X_cov  = (const float*)d_in[1];
    const float* X_lag  = (const float*)d_in[2];
    const float* y      = (const float*)d_in[3];
    const int*   lenw   = (const int*)d_in[5];
    const float* W_ih0  = (const float*)d_in[6];
    const float* W_hh0  = (const float*)d_in[7];
    const float* b_ih0  = (const float*)d_in[8];
    const float* b_hh0  = (const float*)d_in[9];
    const float* W_ih1  = (const float*)d_in[10];
    const float* W_hh1  = (const float*)d_in[11];
    const float* b_ih1  = (const float*)d_in[12];
    const float* b_hh1  = (const float*)d_in[13];
    const float* gate_W = (const float*)d_in[14];
    const float* gate_b = (const float*)d_in[15];
    const float* bn_g   = (const float*)d_in[16];
    const float* bn_b   = (const float*)d_in[17];
    const float* fc_W   = (const float*)d_in[18];
    const float* fc_b   = (const float*)d_in[19];
    float* dout = (float*)d_out;
    float* ws   = (float*)d_ws;

    // workspace layout (float offsets); zp aliases gx0 (dead after gru_xcd),
    // lp_rows aliases x_in (dead after gemm_abt_t)
    float* x_in    = ws;                          // 1,966,080
    unsigned short* gx0bf = (unsigned short*)(ws + 1966080);      // 47,185,920 ush
    unsigned short* out0  = (unsigned short*)(ws + 25559040);     // 15,728,640 ush
    unsigned short* out1  = (unsigned short*)(ws + 33423360);     // 15,728,640 ush
    unsigned short* Whh0bf  = (unsigned short*)(ws + 41287680);   // 786,432 ush
    unsigned short* Wcat1bf = (unsigned short*)(ws + 41680896);   // 1,572,864 ush
    float* zmat    = ws + 42467328;               // 15,360
    float* wm      = ws + 42482688;               // 120
    float* gw_ws   = ws + 42482808;               // 240
    float* msb     = ws + 42483048;               // 61,440
    float* mtb     = ws + 42544488;               // 61,440
    float* part    = ws + 42605928;               // 240
    float* bcomb0  = ws + 42606168;               // 1536
    float* bc1     = ws + 42607704;               // 1536
    int*   flags   = (int*)(ws + 42609240);       // 4096 ints
    int*   rolecnt = (int*)(ws + 42613336);       // 128 ints
    float* zp      = ws + 1966080;                // alias of gx0 region
    float* lp_rows = x_in;                        // alias

    int dsl = (out_size - 2 - 2 * T_SEQ) / (2 * BATCH);   // = 24

    build_x<<<dim3(7680), 256, 0, stream>>>(X_lag, X_cov, x_in);
    cast_whh0<<<dim3(3072), 256, 0, stream>>>(W_hh0, Whh0bf);
    cast_wcat1<<<dim3(6144), 256, 0, stream>>>(W_hh1, W_ih1, Wcat1bf);
    mkbias<<<dim3(6), 256, 0, stream>>>(b_ih0, b_hh0, b_ih1, b_hh1, bcomb0, bc1);
    hipMemsetAsync(flags, 0xFF, 4096 * sizeof(int), stream);   // flags = -1
    hipMemsetAsync(rolecnt, 0, 128 * sizeof(int), stream);

    gemm_abt_t<<<dim3(240, 12), 256, 0, stream>>>(x_in, W_ih0, bcomb0, gx0bf,
                                                  MROWS, G3, 64);

    gru_xcd<<<dim3(320), 256, 0, stream>>>(gx0bf, Whh0bf, Wcat1bf,
                                           b_hh0, bc1, b_hh1,
                                           out0, out1, flags, rolecnt);

    for (int l = 0; l < 2; l++) {
        const unsigned short* o = l ? out1 : out0;
        zpart_kernel<<<960, 256, 0, stream>>>(o, gate_W + (size_t)l * 120 * KGATE, zp);
        zreduce<<<60, 256, 0, stream>>>(zp, gate_b + l * 120, zmat);
        bn_col<<<120, 128, 0, stream>>>(zmat, bn_g + l * 120, bn_b + l * 120, wm);
        softmax120<<<1, 128, 0, stream>>>(wm, dout + 2 + 2 * dsl * 256 + l * 120,
                                          gw_ws + l * 120);
        halfmeans<<<480, 256, 0, stream>>>(o, msb, mtb);
        transfer_part<<<120, 512, 0, stream>>>(msb, mtb, gw_ws + l * 120, lenw,
                                               part + l * 120);
    }

    yhat_kernel<<<dsl * 64, 256, 0, stream>>>(out1, y, fc_W, fc_b, dsl, dout, lp_rows);
    finalize<<<1, 64, 0, stream>>>(lp_rows, part, part + 120, dout, dsl * 256);
}

// Round 10
// 1893.124 us; speedup vs baseline: 3.0061x; 1.0024x over previous
//
#include <hip/hip_runtime.h>
#include <math.h>

#define T_SEQ 120
#define BATCH 256
#define HID   512
#define G3    1536            // 3*HID
#define MROWS (BATCH*T_SEQ)   // 30720
#define TS    (T_SEQ*HID)     // 61440, row stride per batch in out buffers
#define KGATE 122880          // T_SEQ*2*HID
#define FSTRIDE 16            // flag stride (ints) -> one flag per 64B line

typedef __attribute__((ext_vector_type(8))) short bf16x8;
typedef __attribute__((ext_vector_type(4))) float f32x4;

__device__ __forceinline__ unsigned short f2bf(float f) {
    union { float f; unsigned u; } x; x.f = f;
    unsigned r = x.u + 0x7fffu + ((x.u >> 16) & 1u);   // RNE
    return (unsigned short)(r >> 16);
}
__device__ __forceinline__ float bf2f(unsigned short u) {
    union { unsigned u; float f; } x; x.u = ((unsigned)u) << 16; return x.f;
}
__device__ __forceinline__ float sigm_fast(float x) {
    return 1.f / (1.f + __expf(-x));
}
__device__ __forceinline__ float tanh_fast(float x) {
    float e = __expf(2.f * x);
    return 1.f - 2.f / (e + 1.f);
}

// ---------------------------------------------------------------------------
__global__ void build_x(const float* __restrict__ X_lag,
                        const float* __restrict__ X_cov,
                        float* __restrict__ x_in)
{
    int idx = blockIdx.x * 256 + threadIdx.x;      // < 30720*64
    int d = idx & 63;
    int m = idx >> 6;                               // b*120 + t
    int b = m / 120, t = m - b * 120;
    float v;
    if (d < 32) v = X_lag[((size_t)t * BATCH + b) * 32 + d];
    else        v = X_cov[((size_t)t * BATCH + b) * 32 + (d - 32)];
    x_in[idx] = v;
}

__global__ void cast_whh0(const float* __restrict__ W, unsigned short* __restrict__ o)
{
    int i = blockIdx.x * 256 + threadIdx.x;        // < 786432
    o[i] = f2bf(W[i]);
}

// Wcat1 [1536][1024]: cols 0..511 = W_hh1, cols 512..1023 = W_ih1
__global__ void cast_wcat1(const float* __restrict__ Whh, const float* __restrict__ Wih,
                           unsigned short* __restrict__ o)
{
    int i = blockIdx.x * 256 + threadIdx.x;        // < 1572864
    int row = i >> 10, c = i & 1023;
    float v = (c < 512) ? Whh[row * 512 + c] : Wih[row * 512 + (c - 512)];
    o[i] = f2bf(v);
}

__global__ void mkbias(const float* __restrict__ bih0, const float* __restrict__ bhh0,
                       const float* __restrict__ bih1, const float* __restrict__ bhh1,
                       float* __restrict__ bcomb0, float* __restrict__ bc1)
{
    int n = blockIdx.x * 256 + threadIdx.x;        // < 1536
    bcomb0[n] = bih0[n] + (n < 1024 ? bhh0[n] : 0.f);
    bc1[n]    = bih1[n] + (n < 1024 ? bhh1[n] : 0.f);
}

// ---------------------------------------------------------------------------
// Tiled f32 GEMM, bf16 TRANSPOSED write for gx0.   [verified r6-r8]
// ---------------------------------------------------------------------------
__global__ __launch_bounds__(256) void gemm_abt_t(
    const float* __restrict__ A, const float* __restrict__ B,
    const float* __restrict__ bias, unsigned short* __restrict__ C,
    int M, int N, int K)
{
    __shared__ float As[32][129];
    __shared__ float Bs[32][129];
    int m0 = blockIdx.x * 128;
    int n0 = blockIdx.y * 128;
    int tid = threadIdx.x;
    int tx = tid & 15, ty = tid >> 4;
    float acc[8][8] = {};
    for (int k0 = 0; k0 < K; k0 += 32) {
        #pragma unroll
        for (int i = 0; i < 16; i++) {
            int e = tid + i * 256;
            int row = e >> 5, col = e & 31;
            As[col][row] = A[(size_t)(m0 + row) * K + k0 + col];
            Bs[col][row] = B[(size_t)(n0 + row) * K + k0 + col];
        }
        __syncthreads();
        #pragma unroll
        for (int kk = 0; kk < 32; kk++) {
            float a[8], b[8];
            #pragma unroll
            for (int i = 0; i < 8; i++) a[i] = As[kk][ty + i * 16];
            #pragma unroll
            for (int j = 0; j < 8; j++) b[j] = Bs[kk][tx + j * 16];
            #pragma unroll
            for (int i = 0; i < 8; i++)
                #pragma unroll
                for (int j = 0; j < 8; j++) acc[i][j] += a[i] * b[j];
        }
        __syncthreads();
    }
    #pragma unroll
    for (int i = 0; i < 8; i++) {
        int m = m0 + ty + i * 16;
        int b = m / 120, t = m - b * 120;
        #pragma unroll
        for (int j = 0; j < 8; j++) {
            int n = n0 + tx + j * 16;
            C[((size_t)t * 256 + b) * G3 + n] = f2bf(acc[i][j] + bias[n]);
        }
    }
}

// ---------------------------------------------------------------------------
// XCD-partitioned persistent recurrence (round-8 protocol, proven).
// Each physical XCD (HW_REG_XCC_ID) owns batches [xcd*32, xcd*32+32).
// Its 32 resident blocks claim roles via atomicAdd: 0-15 layer0 j-blocks
// (32 cols each), 16-31 layer1. h state IS the bf16 out buffer (fresh
// address every step -> no stale cached line possible). Data: plain stores
// (write-through to XCD L2) + vmcnt(0); flags: AGENT-scope atomics (L3).
// r10 deltas: gx prefetch before wait; batched A-loads; layer-1 split wait.
// ---------------------------------------------------------------------------
__device__ __forceinline__ bool wait16(const int* __restrict__ fb, int thr, int lane)
{
    const int* ap = fb + (lane & 15) * FSTRIDE;
    for (int it = 0; it < 100000; ++it) {
        int v = __hip_atomic_load(ap, __ATOMIC_RELAXED, __HIP_MEMORY_SCOPE_AGENT);
        if (__all(v >= thr)) return true;
        __builtin_amdgcn_s_sleep(1);
    }
    return false;   // hang guard: terminate (wrong) rather than hang
}

__global__ __launch_bounds__(256) void gru_xcd(
    const unsigned short* __restrict__ gx0,          // [120][256][1536] bf16
    const unsigned short* __restrict__ Whh0,         // [1536][512] bf16
    const unsigned short* __restrict__ Wcat1,        // [1536][1024] bf16
    const float* __restrict__ bhh0,
    const float* __restrict__ bc1,
    const float* __restrict__ bhh1,
    unsigned short* __restrict__ out0,               // [256][120][512] bf16
    unsigned short* __restrict__ out1,               // [256][120][512] bf16
    int* __restrict__ flags,                         // [2][8][16] x FSTRIDE
    int* __restrict__ rolecnt)                       // [8] (x16 pad)
{
    __shared__ unsigned short wlds[96 * 520];        // ~97.5 KiB
    __shared__ int role_s;

    int xcd;
    asm("s_getreg_b32 %0, hwreg(20, 0, 32)" : "=s"(xcd));   // HW_REG_XCC_ID
    xcd &= 7;
    if (threadIdx.x == 0) role_s = atomicAdd(&rolecnt[xcd * 16], 1);
    __syncthreads();
    const int role = role_s;
    if (role >= 32) return;

    const int layer = role >> 4;
    const int jb    = role & 15;
    const int j0    = jb * 32;
    const int tid   = threadIdx.x;
    const int w     = tid >> 6, lane = tid & 63;
    const int l15   = lane & 15, l4 = lane >> 4;
    const int jt    = w & 1, bt = w >> 1;
    const int jloc  = jt * 16 + l15;                 // 0..31
    const int j     = j0 + jloc;
    const int bloc0 = bt * 16;                       // 0 or 16
    const int bg0   = xcd * 32;                      // global batch base

    // stage hh-part weights (96 rows x 512) into LDS, padded stride 520
    {
        const unsigned short* Wsrc = layer ? Wcat1 : Whh0;
        const int wstr = layer ? 1024 : 512;
        for (int c = tid; c < 96 * 64; c += 256) {
            int lr = c >> 6, ck = c & 63;
            int grow = (lr >> 5) * 512 + j0 + (lr & 31);
            bf16x8 v = *(const bf16x8*)(Wsrc + (size_t)grow * wstr + ck * 8);
            *(bf16x8*)&wlds[lr * 520 + ck * 8] = v;
        }
    }
    float bn_, br_ = 0.f, bz_ = 0.f, bnx_ = 0.f;
    if (layer) { br_ = bc1[j]; bz_ = bc1[512 + j]; bnx_ = bc1[1024 + j]; bn_ = bhh1[1024 + j]; }
    else       { bn_ = bhh0[1024 + j]; }
    float carry[4] = {0.f, 0.f, 0.f, 0.f};

    const int* f0b = flags + (0 * 8 + xcd) * 16 * FSTRIDE;
    const int* f1b = flags + (1 * 8 + xcd) * 16 * FSTRIDE;
    int* myf = flags + ((layer * 8 + xcd) * 16 + jb) * FSTRIDE;
    __syncthreads();

    if (!layer) {
        // ============================ layer 0 ============================
        for (int t = 0; t < T_SEQ; t++) {
            // prefetch gx0[t] (no h dependency) -- HBM latency hides in poll
            unsigned short gr_[4], gz_[4], gn_[4];
            #pragma unroll
            for (int rr = 0; rr < 4; rr++) {
                int b = bg0 + bloc0 + 4 * l4 + rr;
                const unsigned short* gp = gx0 + ((size_t)t * 256 + b) * G3 + j;
                gr_[rr] = gp[0]; gz_[rr] = gp[512]; gn_[rr] = gp[1024];
            }
            asm volatile("" ::: "memory");           // pin prefetch issue here

            if (!wait16(f0b, t - 1, lane)) break;

            f32x4 a0 = {0,0,0,0}, a1 = {0,0,0,0}, a2 = {0,0,0,0};
            if (t > 0) {
                bf16x8 Areg[16];
                #pragma unroll
                for (int ks = 0; ks < 16; ks++)
                    Areg[ks] = *(const bf16x8*)(out0 + ((size_t)(bg0 + bloc0 + l15) * T_SEQ + (t - 1)) * 512 + ks * 32 + 8 * l4);
                #pragma unroll
                for (int ks = 0; ks < 16; ks++) {
                    const int ko = ks * 32 + 8 * l4;
                    bf16x8 B0 = *(const bf16x8*)&wlds[(0 * 32 + jloc) * 520 + ko];
                    bf16x8 B1 = *(const bf16x8*)&wlds[(1 * 32 + jloc) * 520 + ko];
                    bf16x8 B2 = *(const bf16x8*)&wlds[(2 * 32 + jloc) * 520 + ko];
                    a0 = __builtin_amdgcn_mfma_f32_16x16x32_bf16(Areg[ks], B0, a0, 0, 0, 0);
                    a1 = __builtin_amdgcn_mfma_f32_16x16x32_bf16(Areg[ks], B1, a1, 0, 0, 0);
                    a2 = __builtin_amdgcn_mfma_f32_16x16x32_bf16(Areg[ks], B2, a2, 0, 0, 0);
                }
            }
            #pragma unroll
            for (int rr = 0; rr < 4; rr++) {
                int b = bg0 + bloc0 + 4 * l4 + rr;
                float r = sigm_fast(bf2f(gr_[rr]) + a0[rr]);
                float z = sigm_fast(bf2f(gz_[rr]) + a1[rr]);
                float n = tanh_fast(bf2f(gn_[rr]) + r * (a2[rr] + bn_));
                float h = (1.f - z) * n + z * carry[rr];
                carry[rr] = h;
                out0[((size_t)b * T_SEQ + t) * 512 + j] = f2bf(h);
            }
            asm volatile("s_waitcnt vmcnt(0)" ::: "memory");  // stores in L2
            __syncthreads();
            if (tid == 0)
                __hip_atomic_store(myf, t, __ATOMIC_RELAXED, __HIP_MEMORY_SCOPE_AGENT);
        }
    } else {
        // ============================ layer 1 ============================
        for (int t = 0; t < T_SEQ; t++) {
            f32x4 a0 = {0,0,0,0}, a1 = {0,0,0,0}, a2 = {0,0,0,0}, a3 = {0,0,0,0};
            // hh-part first: only needs own-layer flags >= t-1
            if (!wait16(f1b, t - 1, lane)) break;
            if (t > 0) {
                bf16x8 Areg[16];
                #pragma unroll
                for (int ks = 0; ks < 16; ks++)
                    Areg[ks] = *(const bf16x8*)(out1 + ((size_t)(bg0 + bloc0 + l15) * T_SEQ + (t - 1)) * 512 + ks * 32 + 8 * l4);
                #pragma unroll
                for (int ks = 0; ks < 16; ks++) {
                    const int ko = ks * 32 + 8 * l4;
                    bf16x8 B0 = *(const bf16x8*)&wlds[(0 * 32 + jloc) * 520 + ko];
                    bf16x8 B1 = *(const bf16x8*)&wlds[(1 * 32 + jloc) * 520 + ko];
                    bf16x8 B2 = *(const bf16x8*)&wlds[(2 * 32 + jloc) * 520 + ko];
                    a0 = __builtin_amdgcn_mfma_f32_16x16x32_bf16(Areg[ks], B0, a0, 0, 0, 0);
                    a1 = __builtin_amdgcn_mfma_f32_16x16x32_bf16(Areg[ks], B1, a1, 0, 0, 0);
                    a2 = __builtin_amdgcn_mfma_f32_16x16x32_bf16(Areg[ks], B2, a2, 0, 0, 0);
                }
            }
            // x-part: needs layer0 flags >= t
            if (!wait16(f0b, t, lane)) break;
            {
                bf16x8 Areg[16];
                #pragma unroll
                for (int ks = 0; ks < 16; ks++)
                    Areg[ks] = *(const bf16x8*)(out0 + ((size_t)(bg0 + bloc0 + l15) * T_SEQ + t) * 512 + ks * 32 + 8 * l4);
                #pragma unroll
                for (int ks = 0; ks < 16; ks++) {
                    const int ko = ks * 32 + 8 * l4;
                    const unsigned short* wb = Wcat1 + (size_t)j * 1024 + 512 + ko;
                    bf16x8 B0 = *(const bf16x8*)(wb);
                    bf16x8 B1 = *(const bf16x8*)(wb + 512 * 1024);
                    bf16x8 B2 = *(const bf16x8*)(wb + 1024 * 1024);
                    a0 = __builtin_amdgcn_mfma_f32_16x16x32_bf16(Areg[ks], B0, a0, 0, 0, 0);
                    a1 = __builtin_amdgcn_mfma_f32_16x16x32_bf16(Areg[ks], B1, a1, 0, 0, 0);
                    a3 = __builtin_amdgcn_mfma_f32_16x16x32_bf16(Areg[ks], B2, a3, 0, 0, 0);
                }
            }
            #pragma unroll
            for (int rr = 0; rr < 4; rr++) {
                int b = bg0 + bloc0 + 4 * l4 + rr;
                float r = sigm_fast(a0[rr] + br_);
                float z = sigm_fast(a1[rr] + bz_);
                float n = tanh_fast(a3[rr] + bnx_ + r * (a2[rr] + bn_));
                float h = (1.f - z) * n + z * carry[rr];
                carry[rr] = h;
                out1[((size_t)b * T_SEQ + t) * 512 + j] = f2bf(h);
            }
            asm volatile("s_waitcnt vmcnt(0)" ::: "memory");
            __syncthreads();
            if (tid == 0)
                __hip_atomic_store(myf, t, __ATOMIC_RELAXED, __HIP_MEMORY_SCOPE_AGENT);
        }
    }
}

// ---------------------------------------------------------------------------
// z partials (bf16 out reader): 960 blocks = (t, half, c-quarter).  [r8 ok]
// ---------------------------------------------------------------------------
__global__ __launch_bounds__(256) void zpart_kernel(
    const unsigned short* __restrict__ out, const float* __restrict__ Gw,
    float* __restrict__ zp)
{
    __shared__ float Os[128][33];
    __shared__ float Gs[128][33];
    int bk = blockIdx.x;
    int t = bk >> 3, half = (bk >> 2) & 1, cq = bk & 3;
    int tid = threadIdx.x;
    int tx = tid & 15, ty = tid >> 4;
    float acc[8][8] = {};
    int cbase = cq * 128;
    for (int c0 = cbase; c0 < cbase + 128; c0 += 32) {
        #pragma unroll
        for (int i = 0; i < 16; i++) {
            int e = tid + i * 256;
            int row = e >> 5, col = e & 31;
            Os[row][col] = bf2f(out[((size_t)(row + half * 128) * T_SEQ + t) * 512 + c0 + col]);
            float v = 0.f;
            if (row < 120)
                v = Gw[(size_t)row * KGATE + (size_t)t * 1024 + half * 512 + c0 + col];
            Gs[row][col] = v;
        }
        __syncthreads();
        #pragma unroll
        for (int kk = 0; kk < 32; kk++) {
            float a[8], g[8];
            #pragma unroll
            for (int i = 0; i < 8; i++) a[i] = Os[ty + i * 16][kk];
            #pragma unroll
            for (int j = 0; j < 8; j++) g[j] = Gs[tx + j * 16][kk];
            #pragma unroll
            for (int i = 0; i < 8; i++)
                #pragma unroll
                for (int j = 0; j < 8; j++) acc[i][j] += a[i] * g[j];
        }
        __syncthreads();
    }
    float* zb = zp + (size_t)bk * (128 * 120);
    #pragma unroll
    for (int i = 0; i < 8; i++) {
        int ii = ty + i * 16;
        #pragma unroll
        for (int j = 0; j < 8; j++) {
            int r = tx + j * 16;
            if (r < 120) zb[ii * 120 + r] = acc[i][j];
        }
    }
}

__global__ void zreduce(const float* __restrict__ zp,
                        const float* __restrict__ gate_b_l,
                        float* __restrict__ z)
{
    int idx = blockIdx.x * 256 + threadIdx.x;
    if (idx >= 128 * 120) return;
    float s = 0.f;
    for (int c = 0; c < 960; c++) s += zp[(size_t)c * (128 * 120) + idx];
    z[idx] = s + gate_b_l[idx % 120];
}

__global__ __launch_bounds__(128) void bn_col(
    const float* __restrict__ z, const float* __restrict__ gamma,
    const float* __restrict__ beta, float* __restrict__ wm)
{
    int r = blockIdx.x, i = threadIdx.x;
    __shared__ float sh[2];
    float v = z[i * 120 + r];
    float s = v;
    for (int o = 32; o > 0; o >>= 1) s += __shfl_down(s, o);
    if ((i & 63) == 0) sh[i >> 6] = s;
    __syncthreads();
    float m = (sh[0] + sh[1]) * (1.f / 128.f);
    __syncthreads();
    float d = (v - m) * (v - m);
    for (int o = 32; o > 0; o >>= 1) d += __shfl_down(d, o);
    if ((i & 63) == 0) sh[i >> 6] = d;
    __syncthreads();
    float var = (sh[0] + sh[1]) * (1.f / 128.f);
    float w = 1.f / (1.f + expf(-(gamma[r] * (v - m) / sqrtf(var + 1e-5f) + beta[r])));
    __syncthreads();
    float ws_ = w;
    for (int o = 32; o > 0; o >>= 1) ws_ += __shfl_down(ws_, o);
    if ((i & 63) == 0) sh[i >> 6] = ws_;
    __syncthreads();
    if (i == 0) wm[r] = (sh[0] + sh[1]) * (1.f / 128.f);
}

__global__ __launch_bounds__(128) void softmax120(
    const float* __restrict__ wm, float* __restrict__ g_out,
    float* __restrict__ g_ws)
{
    int i = threadIdx.x;
    __shared__ float sh[2];
    float v = (i < 120) ? wm[i] : -1e30f;
    float m = v;
    for (int o = 32; o > 0; o >>= 1) m = fmaxf(m, __shfl_down(m, o));
    if ((i & 63) == 0) sh[i >> 6] = m;
    __syncthreads();
    float mx = fmaxf(sh[0], sh[1]);
    float e = (i < 120) ? expf(v - mx) : 0.f;
    __syncthreads();
    float se = e;
    for (int o = 32; o > 0; o >>= 1) se += __shfl_down(se, o);
    if ((i & 63) == 0) sh[i >> 6] = se;
    __syncthreads();
    float sum = sh[0] + sh[1];
    if (i < 120) { float g = e / sum; g_out[i] = g; g_ws[i] = g; }
}

__global__ void halfmeans(const unsigned short* __restrict__ out,
                          float* __restrict__ ms, float* __restrict__ mt)
{
    int idx = blockIdx.x * 256 + threadIdx.x;
    int half = idx >= TS;
    int tc = idx - half * TS;
    const unsigned short* base = out + (size_t)(half * 128) * TS + tc;
    float s = 0.f;
    for (int i = 0; i < 128; i++) s += bf2f(base[(size_t)i * TS]);
    s *= (1.f / 128.f);
    if (half) mt[tc] = s; else ms[tc] = s;
}

__global__ __launch_bounds__(512) void transfer_part(
    const float* __restrict__ ms, const float* __restrict__ mt,
    const float* __restrict__ gw, const int* __restrict__ lenw,
    float* __restrict__ part)
{
    int t = blockIdx.x, c = threadIdx.x;
    int lw = lenw[0];
    int j0 = t - lw; if (j0 < 0) j0 = 0;
    int j1 = t + lw; if (j1 > 119) j1 = 119;
    float m_c = ms[(size_t)t * 512 + c];
    float acc = 0.f;
    for (int j = j0; j <= j1; j++) {
        float d = m_c - mt[(size_t)j * 512 + c];
        acc += d * d;
    }
    for (int o = 32; o > 0; o >>= 1) acc += __shfl_down(acc, o);
    __shared__ float sh[8];
    if ((c & 63) == 0) sh[c >> 6] = acc;
    __syncthreads();
    if (c == 0) {
        float s = 0.f;
        #pragma unroll
        for (int k = 0; k < 8; k++) s += sh[k];
        part[t] = gw[t] * s;
    }
}

__global__ __launch_bounds__(256) void yhat_kernel(
    const unsigned short* __restrict__ out1, const float* __restrict__ y,
    const float* __restrict__ fcW, const float* __restrict__ fcb,
    int dsl, float* __restrict__ dout, float* __restrict__ lp_rows)
{
    int wid = blockIdx.x * 4 + (threadIdx.x >> 6);   // 0..dsl*256-1
    int lane = threadIdx.x & 63;
    int tt = wid >> 8, b = wid & 255;
    int t = T_SEQ - dsl + tt;
    const unsigned short* row = out1 + ((size_t)b * T_SEQ + t) * 512;
    float s = 0.f;
    #pragma unroll
    for (int k = 0; k < 8; k++) s += bf2f(row[lane + 64 * k]) * fcW[lane + 64 * k];
    for (int o = 32; o > 0; o >>= 1) s += __shfl_down(s, o);
    if (lane == 0) {
        float loc = s + fcb[0];
        float sp = fmaxf(loc, 0.f) + log1pf(expf(-fabsf(loc)));
        float scale = sp + 1e-6f;
        dout[2 + tt * 256 + b] = loc;
        dout[2 + dsl * 256 + tt * 256 + b] = scale;
        float yt = y[(size_t)t * 256 + b];
        float u = (yt - loc) / scale;
        lp_rows[wid] = -0.5f * u * u - logf(scale) - 0.91893853320467274f;
    }
}

__global__ __launch_bounds__(64) void finalize(
    const float* __restrict__ lp_rows, const float* __restrict__ part0,
    const float* __restrict__ part1, float* __restrict__ dout, int n_lp)
{
    int i = threadIdx.x;
    float s = 0.f;
    for (int k = i; k < n_lp; k += 64) s += lp_rows[k];
    for (int o = 32; o > 0; o >>= 1) s += __shfl_down(s, o);
    float tr = 0.f;
    for (int k = i; k < 120; k += 64) tr += part0[k] + part1[k];
    for (int o = 32; o > 0; o >>= 1) tr += __shfl_down(tr, o);
    if (i == 0) {
        float ly = -s / (float)n_lp;
        dout[1] = ly;
        dout[0] = ly + tr;
    }
}

// ---------------------------------------------------------------------------
extern "C" void kernel_launch(void* const* d_in, const int* in_sizes, int n_in,
                              void* d_out, int out_size, void* d_ws, size_t ws_size,
                              hipStream_t stream)
{
    const float* X_cov  = (const float*)d_in[1];
    const float* X_lag  = (const float*)d_in[2];
    const float* y      = (const float*)d_in[3];
    const int*   lenw   = (const int*)d_in[5];
    const float* W_ih0  = (const float*)d_in[6];
    const float* W_hh0  = (const float*)d_in[7];
    const float* b_ih0  = (const float*)d_in[8];
    const float* b_hh0  = (const float*)d_in[9];
    const float* W_ih1  = (const float*)d_in[10];
    const float* W_hh1  = (const float*)d_in[11];
    const float* b_ih1  = (const float*)d_in[12];
    const float* b_hh1  = (const float*)d_in[13];
    const float* gate_W = (const float*)d_in[14];
    const float* gate_b = (const float*)d_in[15];
    const float* bn_g   = (const float*)d_in[16];
    const float* bn_b   = (const float*)d_in[17];
    const float* fc_W   = (const float*)d_in[18];
    const float* fc_b   = (const float*)d_in[19];
    float* dout = (float*)d_out;
    float* ws   = (float*)d_ws;

    // workspace layout (float offsets); zp aliases gx0 (dead after gru_xcd),
    // lp_rows aliases x_in (dead after gemm_abt_t)
    float* x_in    = ws;                          // 1,966,080
    unsigned short* gx0bf = (unsigned short*)(ws + 1966080);      // 47,185,920 ush
    unsigned short* out0  = (unsigned short*)(ws + 25559040);     // 15,728,640 ush
    unsigned short* out1  = (unsigned short*)(ws + 33423360);     // 15,728,640 ush
    unsigned short* Whh0bf  = (unsigned short*)(ws + 41287680);   // 786,432 ush
    unsigned short* Wcat1bf = (unsigned short*)(ws + 41680896);   // 1,572,864 ush
    float* zmat    = ws + 42467328;               // 15,360
    float* wm      = ws + 42482688;               // 120
    float* gw_ws   = ws + 42482808;               // 240
    float* msb     = ws + 42483048;               // 61,440
    float* mtb     = ws + 42544488;               // 61,440
    float* part    = ws + 42605928;               // 240
    float* bcomb0  = ws + 42606168;               // 1536
    float* bc1     = ws + 42607704;               // 1536
    int*   flags   = (int*)(ws + 42609240);       // 4096 ints
    int*   rolecnt = (int*)(ws + 42613336);       // 128 ints
    float* zp      = ws + 1966080;                // alias of gx0 region
    float* lp_rows = x_in;                        // alias

    int dsl = (out_size - 2 - 2 * T_SEQ) / (2 * BATCH);   // = 24

    build_x<<<dim3(7680), 256, 0, stream>>>(X_lag, X_cov, x_in);
    cast_whh0<<<dim3(3072), 256, 0, stream>>>(W_hh0, Whh0bf);
    cast_wcat1<<<dim3(6144), 256, 0, stream>>>(W_hh1, W_ih1, Wcat1bf);
    mkbias<<<dim3(6), 256, 0, stream>>>(b_ih0, b_hh0, b_ih1, b_hh1, bcomb0, bc1);
    hipMemsetAsync(flags, 0xFF, 4096 * sizeof(int), stream);   // flags = -1
    hipMemsetAsync(rolecnt, 0, 128 * sizeof(int), stream);

    gemm_abt_t<<<dim3(240, 12), 256, 0, stream>>>(x_in, W_ih0, bcomb0, gx0bf,
                                                  MROWS, G3, 64);

    gru_xcd<<<dim3(320), 256, 0, stream>>>(gx0bf, Whh0bf, Wcat1bf,
                                           b_hh0, bc1, b_hh1,
                                           out0, out1, flags, rolecnt);

    for (int l = 0; l < 2; l++) {
        const unsigned short* o = l ? out1 : out0;
        zpart_kernel<<<960, 256, 0, stream>>>(o, gate_W + (size_t)l * 120 * KGATE, zp);
        zreduce<<<60, 256, 0, stream>>>(zp, gate_b + l * 120, zmat);
        bn_col<<<120, 128, 0, stream>>>(zmat, bn_g + l * 120, bn_b + l * 120, wm);
        softmax120<<<1, 128, 0, stream>>>(wm, dout + 2 + 2 * dsl * 256 + l * 120,
                                          gw_ws + l * 120);
        halfmeans<<<480, 256, 0, stream>>>(o, msb, mtb);
        transfer_part<<<120, 512, 0, stream>>>(msb, mtb, gw_ws + l * 120, lenw,
                                               part + l * 120);
    }

    yhat_kernel<<<dsl * 64, 256, 0, stream>>>(out1, y, fc_W, fc_b, dsl, dout, lp_rows);
    finalize<<<1, 64, 0, stream>>>(lp_rows, part, part + 120, dout, dsl * 256);
}